// Round 9
// baseline (1316.447 us; speedup 1.0000x reference)
//
#include <hip/hip_runtime.h>

// Problem constants (match reference setup_inputs)
constexpr int NVn = 200000;   // var nodes, 9 feats in
constexpr int NCn = 100000;   // cstr nodes, 1 feat in
constexpr int NEn = 1000000;  // edges
constexpr int NBb = 32;       // graphs
#define EPSf 1e-5f

typedef __attribute__((ext_vector_type(8))) short s8v;   // 8 bf16 (4 VGPRs)
typedef __attribute__((ext_vector_type(4))) float f4v;   // 4 f32 acc

// f32 -> bf16 bits, round-to-nearest-even
static __device__ __forceinline__ unsigned short f2b(float f) {
    union { float f; unsigned u; } x; x.f = f;
    return (unsigned short)((x.u + 0x7FFFu + ((x.u >> 16) & 1u)) >> 16);
}

// load 8 consecutive f32, convert to bf16x8 fragment
static __device__ __forceinline__ s8v cvt8(const float* p) {
    float4 a = *(const float4*)p;
    float4 b = *(const float4*)(p + 4);
    s8v r;
    r[0] = (short)f2b(a.x); r[1] = (short)f2b(a.y); r[2] = (short)f2b(a.z); r[3] = (short)f2b(a.w);
    r[4] = (short)f2b(b.x); r[5] = (short)f2b(b.y); r[6] = (short)f2b(b.z); r[7] = (short)f2b(b.w);
    return r;
}

// store folded weight W[kg][h] (kg in 0..127, h in 0..63) into MFMA B-fragment order:
// fragment (ks=kg>>5, ct=h>>4), lane = ((kg>>3)&3)<<4 | (h&15), elem j = kg&7
static __device__ __forceinline__ void frag_store(unsigned short* B, int kg, int h, float w) {
    int ks = kg >> 5, g = (kg >> 3) & 3, j = kg & 7, ct = h >> 4;
    int lane = (g << 4) | (h & 15);
    B[((((ks << 2) | ct) << 6) | lane) * 8 + j] = f2b(w);
}

// ---------------- degree count ----------------
__global__ __launch_bounds__(256) void k_count_deg(const int* __restrict__ src, const int* __restrict__ dst,
                            int* __restrict__ degv, int* __restrict__ degc) {
    for (int e = blockIdx.x * blockDim.x + threadIdx.x; e < NEn; e += gridDim.x * blockDim.x) {
        atomicAdd(&degv[dst[e]], 1);
        atomicAdd(&degc[src[e]], 1);
    }
}

// ---------------- exclusive scan (3 kernels, 1024 elems/block) ----------------
__global__ __launch_bounds__(256) void k_scan_block(const int* __restrict__ deg, int n, int* __restrict__ bsum) {
    __shared__ int s[256];
    int base = blockIdx.x * 1024;
    int t = threadIdx.x;
    int v = 0;
#pragma unroll
    for (int j = 0; j < 4; j++) { int idx = base + t * 4 + j; if (idx < n) v += deg[idx]; }
    s[t] = v; __syncthreads();
    for (int o = 128; o > 0; o >>= 1) { if (t < o) s[t] += s[t + o]; __syncthreads(); }
    if (t == 0) bsum[blockIdx.x] = s[0];
}

__global__ __launch_bounds__(1024) void k_scan_tops(int* bsum, int nb) {
    __shared__ int s[1024];
    int t = threadIdx.x;
    int v = (t < nb) ? bsum[t] : 0;
    s[t] = v; __syncthreads();
    for (int o = 1; o < 1024; o <<= 1) {
        int x = (t >= o) ? s[t - o] : 0; __syncthreads();
        s[t] += x; __syncthreads();
    }
    if (t < nb) bsum[t] = s[t] - v;  // exclusive
}

__global__ __launch_bounds__(256) void k_scan_final(const int* __restrict__ deg, int n, const int* __restrict__ bsum,
                             int* __restrict__ off, int* __restrict__ cur) {
    __shared__ int s[256];
    int base = blockIdx.x * 1024, t = threadIdx.x;
    int d[4], loc[4], sum = 0;
#pragma unroll
    for (int j = 0; j < 4; j++) {
        int idx = base + t * 4 + j;
        d[j] = (idx < n) ? deg[idx] : 0;
        loc[j] = sum; sum += d[j];
    }
    s[t] = sum; __syncthreads();
    int v = sum;
    for (int o = 1; o < 256; o <<= 1) {
        int x = (t >= o) ? s[t - o] : 0; __syncthreads();
        s[t] += x; __syncthreads();
    }
    int texcl = s[t] - v + bsum[blockIdx.x];
#pragma unroll
    for (int j = 0; j < 4; j++) {
        int idx = base + t * 4 + j;
        if (idx < n) {
            int o2 = texcl + loc[j];
            off[idx] = o2; cur[idx] = o2;
            if (idx == n - 1) off[n] = o2 + d[j];
        }
    }
}

// ---------------- CSR fill (w = ew / deg) ----------------
__global__ __launch_bounds__(256) void k_fill(const int* __restrict__ key, const int* __restrict__ other,
                       const float* __restrict__ ew, const int* __restrict__ off,
                       int* __restrict__ cur, int* __restrict__ col, float* __restrict__ w) {
    for (int e = blockIdx.x * blockDim.x + threadIdx.x; e < NEn; e += gridDim.x * blockDim.x) {
        int d = key[e];
        int p = atomicAdd(&cur[d], 1);
        col[p] = other[e];
        float invd = 1.0f / (float)(off[d + 1] - off[d]);
        w[p] = ew[e] * invd;
    }
}

__global__ __launch_bounds__(256) void k_wsum(const int* __restrict__ off, const float* __restrict__ w,
                       float* __restrict__ ws, int n) {
    for (int i = blockIdx.x * blockDim.x + threadIdx.x; i < n; i += gridDim.x * blockDim.x) {
        int s = off[i], e = off[i + 1]; float t = 0.f;
        for (int j = s; j < e; j++) t += w[j];
        ws[i] = t;
    }
}

// ---------------- BN column stats ----------------
// Round-8 fix: grid 1024->2048 (2048 blk x 4 waves = 8192 waves = chip capacity),
// one LDS pass (sum+sumsq together), 128 atomics/block.
__global__ __launch_bounds__(256) void k_stats64(const float* __restrict__ x, int n, float* __restrict__ acc) {
    int c = threadIdx.x & 63, r4 = threadIdx.x >> 6;
    float s = 0.f, q = 0.f;
    for (int i = blockIdx.x * 4 + r4; i < n; i += gridDim.x * 4) {
        float v = x[(size_t)i * 64 + c]; s += v; q = fmaf(v, v, q);
    }
    __shared__ float ls[512];
    ls[threadIdx.x] = s; ls[256 + threadIdx.x] = q;
    __syncthreads();
    if (r4 == 0) {
        atomicAdd(&acc[c], ls[c] + ls[c + 64] + ls[c + 128] + ls[c + 192]);
        atomicAdd(&acc[64 + c], ls[256 + c] + ls[256 + c + 64] + ls[256 + c + 128] + ls[256 + c + 192]);
    }
}

// Round-8 fix: was 128 blocks + 18 global atomics PER THREAD (590K contended atomics,
// 35 GB/s, 110 us). Now: 1 row/thread grid, wave shuffle-reduce, LDS cross-wave,
// 2D atomics per block (14K total).
template <int D>
__global__ __launch_bounds__(256) void k_stats_small(const float* __restrict__ x, int n, float* __restrict__ acc) {
    float s[D], q[D];
#pragma unroll
    for (int k = 0; k < D; k++) { s[k] = 0.f; q[k] = 0.f; }
    for (int i = blockIdx.x * blockDim.x + threadIdx.x; i < n; i += gridDim.x * blockDim.x) {
#pragma unroll
        for (int k = 0; k < D; k++) { float v = x[(size_t)i * D + k]; s[k] += v; q[k] = fmaf(v, v, q[k]); }
    }
    // wave butterfly reduce
#pragma unroll
    for (int k = 0; k < D; k++) {
#pragma unroll
        for (int o = 32; o > 0; o >>= 1) {
            s[k] += __shfl_down(s[k], o);
            q[k] += __shfl_down(q[k], o);
        }
    }
    __shared__ float ls[4][2 * D];
    int lane = threadIdx.x & 63, wv = threadIdx.x >> 6;
    if (lane == 0) {
#pragma unroll
        for (int k = 0; k < D; k++) { ls[wv][k] = s[k]; ls[wv][D + k] = q[k]; }
    }
    __syncthreads();
    int t = threadIdx.x;
    if (t < 2 * D) atomicAdd(&acc[t], ls[0][t] + ls[1][t] + ls[2][t] + ls[3][t]);
}

// ---------------- fold BN into weights (parallel: 256 thr, 4 waves split k-range) ----------
__global__ __launch_bounds__(256) void k_fold(const float* __restrict__ Wrel, const float* __restrict__ brel,
                       const float* __restrict__ Wroot,
                       const float* __restrict__ gs, const float* __restrict__ bs,
                       const float* __restrict__ accs, float invNs, int DSv,
                       const float* __restrict__ gd, const float* __restrict__ bd,
                       const float* __restrict__ accd, float invNd, int DDv,
                       float* __restrict__ Wr_o, float* __restrict__ Wt_o,
                       float* __restrict__ b0_o, float* __restrict__ bw_o,
                       unsigned short* __restrict__ Bfrag) {
    __shared__ float sa[128], sbe[128];
    __shared__ float rb0[4][64], rbw[4][64];
    int t = threadIdx.x;
    int total = DSv + DDv;
    for (int k = t; k < total; k += 256) {
        bool isrc = k < DSv;
        int kk = isrc ? k : k - DSv;
        const float* acc = isrc ? accs : accd;
        float invN = isrc ? invNs : invNd;
        int D = isrc ? DSv : DDv;
        float g = isrc ? gs[kk] : gd[kk];
        float b = isrc ? bs[kk] : bd[kk];
        float m = acc[kk] * invN;
        float var = acc[D + kk] * invN - m * m;
        float a = g * rsqrtf(var + EPSf);
        sa[k] = a; sbe[k] = b - m * a;
    }
    __syncthreads();
    int h = t & 63, q = t >> 6;
    float bw = 0.f, b0 = 0.f;
    for (int k = q; k < DSv; k += 4) {
        float wv = Wrel[k * 64 + h];
        float wf = sa[k] * wv;
        Wr_o[k * 64 + h] = wf;
        bw = fmaf(sbe[k], wv, bw);
        if (Bfrag) frag_store(Bfrag, k, h, wf);
    }
    for (int k = q; k < DDv; k += 4) {
        float wv = Wroot[k * 64 + h];
        float wf = sa[DSv + k] * wv;
        Wt_o[k * 64 + h] = wf;
        b0 = fmaf(sbe[DSv + k], wv, b0);
        if (Bfrag) frag_store(Bfrag, 64 + k, h, wf);
    }
    rb0[q][h] = b0; rbw[q][h] = bw;
    __syncthreads();
    if (q == 0) {
        b0_o[h] = brel[h] + rb0[0][h] + rb0[1][h] + rb0[2][h] + rb0[3][h];
        bw_o[h] = rbw[0][h] + rbw[1][h] + rbw[2][h] + rbw[3][h];
    }
}

// ---------------- aggregation (gather form from CSR) ----------------
// wave per node; lane = feature; 4-way unrolled edge loop for memory-level parallelism
template <int DS>
__global__ __launch_bounds__(256) void k_agg(const float* __restrict__ xs, const int* __restrict__ off,
                      const int* __restrict__ col, const float* __restrict__ w,
                      float* __restrict__ agg, int n) {
    int lane = threadIdx.x & 63;
    int wid = (blockIdx.x * blockDim.x + threadIdx.x) >> 6;
    int nw = (gridDim.x * blockDim.x) >> 6;
    for (int i = wid; i < n; i += nw) {
        int s = off[i], e = off[i + 1];
        if (lane < DS) {
            float a0 = 0.f, a1 = 0.f, a2 = 0.f, a3 = 0.f;
            int j = s;
            for (; j + 3 < e; j += 4) {
                int c0 = col[j], c1 = col[j + 1], c2 = col[j + 2], c3 = col[j + 3];
                float w0 = w[j], w1 = w[j + 1], w2 = w[j + 2], w3 = w[j + 3];
                a0 = fmaf(w0, xs[(size_t)c0 * DS + lane], a0);
                a1 = fmaf(w1, xs[(size_t)c1 * DS + lane], a1);
                a2 = fmaf(w2, xs[(size_t)c2 * DS + lane], a2);
                a3 = fmaf(w3, xs[(size_t)c3 * DS + lane], a3);
            }
            for (; j < e; j++) a0 = fmaf(w[j], xs[(size_t)col[j] * DS + lane], a0);
            agg[(size_t)i * DS + lane] = (a0 + a1) + (a2 + a3);
        }
    }
}

// DS==1 specialization: thread per node
__global__ __launch_bounds__(256) void k_agg1(const float* __restrict__ xs, const int* __restrict__ off,
                       const int* __restrict__ col, const float* __restrict__ w,
                       float* __restrict__ agg, int n) {
    for (int i = blockIdx.x * blockDim.x + threadIdx.x; i < n; i += gridDim.x * blockDim.x) {
        int s = off[i], e = off[i + 1]; float a = 0.f;
        for (int j = s; j < e; j++) a = fmaf(w[j], xs[col[j]], a);
        agg[i] = a;
    }
}

// ---------------- layer-0 small-K GEMM: thread per (node, h) ----------------
template <int KS, int KD>
__global__ __launch_bounds__(256) void k_gemm0(const float* __restrict__ aggs, const float* __restrict__ xd,
                        const float* __restrict__ wsum,
                        const float* __restrict__ Wr, const float* __restrict__ Wt,
                        const float* __restrict__ b0, const float* __restrict__ bw,
                        float* __restrict__ out, int n) {
    int idx = blockIdx.x * blockDim.x + threadIdx.x;
    int i = idx >> 6, h = idx & 63;
    if (i >= n) return;
    float acc = b0[h] + wsum[i] * bw[h];
#pragma unroll
    for (int k = 0; k < KS; k++) acc = fmaf(aggs[i * KS + k], Wr[k * 64 + h], acc);
#pragma unroll
    for (int k = 0; k < KD; k++) acc = fmaf(xd[i * KD + k], Wt[k * 64 + h], acc);
    out[i * 64 + h] = fmaxf(acc, 0.0f);
}

// ---------------- main GEMM via MFMA bf16 ----------------
// out[n][64] = relu([agg|x][n][128] @ Bfrag[128][64] + b0 + wsum*bw)
// Block = 256 thr = 4 waves; wave w owns rows [blk*64 + 16w, +16), all 64 cols.
// Per wave: 4 k-steps x 4 col-tiles = 16 x mfma_f32_16x16x32_bf16, acc = 4x f32x4 (AGPR).
// No LDS, no __syncthreads, no per-thread arrays -> cannot spill.
// agg and out alias in-place: each wave reads/writes only its own 16 rows.
__global__ __launch_bounds__(256, 4) void k_gemm(const float* agg, const float* __restrict__ xroot,
                       const float* __restrict__ wsum, const unsigned short* __restrict__ Bfrag,
                       const float* __restrict__ b0, const float* __restrict__ bwv,
                       float* out, int n) {
    int t = threadIdx.x;
    int wv = t >> 6, l = t & 63;
    int lrow = l & 15, lkg = l >> 4;
    int base = blockIdx.x * 64 + wv * 16;
    int arow = base + lrow;
    if (arow >= n) arow = 0;                 // safe redirect for tail block
    const float* ap = agg + (size_t)arow * 64 + lkg * 8;
    const float* xp = xroot + (size_t)arow * 64 + lkg * 8;
    const unsigned short* Bl = Bfrag + l * 8;
    f4v acc0 = {0.f, 0.f, 0.f, 0.f};
    f4v acc1 = acc0, acc2 = acc0, acc3 = acc0;
#define KSTEP(ks, P)                                                        \
    {                                                                       \
        s8v a = cvt8(P);                                                    \
        s8v f0 = *(const s8v*)(Bl + ((ks) * 4 + 0) * 512);                  \
        s8v f1 = *(const s8v*)(Bl + ((ks) * 4 + 1) * 512);                  \
        s8v f2 = *(const s8v*)(Bl + ((ks) * 4 + 2) * 512);                  \
        s8v f3 = *(const s8v*)(Bl + ((ks) * 4 + 3) * 512);                  \
        acc0 = __builtin_amdgcn_mfma_f32_16x16x32_bf16(a, f0, acc0, 0, 0, 0); \
        acc1 = __builtin_amdgcn_mfma_f32_16x16x32_bf16(a, f1, acc1, 0, 0, 0); \
        acc2 = __builtin_amdgcn_mfma_f32_16x16x32_bf16(a, f2, acc2, 0, 0, 0); \
        acc3 = __builtin_amdgcn_mfma_f32_16x16x32_bf16(a, f3, acc3, 0, 0, 0); \
    }
    KSTEP(0, ap)
    KSTEP(1, ap + 32)
    KSTEP(2, xp)
    KSTEP(3, xp + 32)
#undef KSTEP
    // epilogue: C/D layout col = l&15 (+16*ct), row = 4*(l>>4) + reg
    int orow = base + lkg * 4;
    float ws0 = (orow + 0 < n) ? wsum[orow + 0] : 0.f;
    float ws1 = (orow + 1 < n) ? wsum[orow + 1] : 0.f;
    float ws2 = (orow + 2 < n) ? wsum[orow + 2] : 0.f;
    float ws3 = (orow + 3 < n) ? wsum[orow + 3] : 0.f;
#define EPI(ACC, ct)                                                                        \
    {                                                                                       \
        int c = (ct) * 16 + lrow;                                                           \
        float bb = b0[c], wb = bwv[c];                                                      \
        if (orow + 0 < n) out[(size_t)(orow + 0) * 64 + c] = fmaxf(ACC[0] + bb + ws0 * wb, 0.f); \
        if (orow + 1 < n) out[(size_t)(orow + 1) * 64 + c] = fmaxf(ACC[1] + bb + ws1 * wb, 0.f); \
        if (orow + 2 < n) out[(size_t)(orow + 2) * 64 + c] = fmaxf(ACC[2] + bb + ws2 * wb, 0.f); \
        if (orow + 3 < n) out[(size_t)(orow + 3) * 64 + c] = fmaxf(ACC[3] + bb + ws3 * wb, 0.f); \
    }
    EPI(acc0, 0)
    EPI(acc1, 1)
    EPI(acc2, 2)
    EPI(acc3, 3)
#undef EPI
}

// ---------------- pooling ----------------
__global__ __launch_bounds__(256) void k_seg_count(const int* __restrict__ batch, int n, int* __restrict__ cnt) {
    int i = blockIdx.x * blockDim.x + threadIdx.x;
    if (i >= n) return;
    int lane = threadIdx.x & 63;
    int b = batch[i];
    int bprev = __shfl_up(b, 1);
    bool head = (lane == 0) || (b != bprev);
    unsigned long long hb = __ballot(head);
    if (head) {
        unsigned long long mask = (lane == 63) ? 0ULL : (hb >> (lane + 1));
        int wstart = i - lane;
        int nvalid = min(64, n - wstart);
        int end = (mask == 0ULL) ? nvalid : (lane + 1 + __ffsll((long long)mask) - 1);
        atomicAdd(&cnt[b], end - lane);
    }
}

// 128 rows/block (32/walker), grid ~1563: BW-bound. batch sorted -> ~1 run/walker.
__global__ __launch_bounds__(256) void k_pool_accum(const float* __restrict__ x, const int* __restrict__ batch,
                             int n, float* __restrict__ sums) {
    int c = threadIdx.x & 63, r4 = threadIdx.x >> 6;
    int base = blockIdx.x * 128 + r4 * 32;
    int end = min(n, base + 32);
    float acc = 0.f; int cur = -1;
    for (int i = base; i < end; ++i) {
        int b = batch[i];
        if (b != cur) {
            if (cur >= 0) atomicAdd(&sums[cur * 64 + c], acc);
            acc = 0.f; cur = b;
        }
        acc += x[(size_t)i * 64 + c];
    }
    if (cur >= 0) atomicAdd(&sums[cur * 64 + c], acc);
}

__global__ __launch_bounds__(256) void k_pool_div(const float* __restrict__ sv, const float* __restrict__ sc,
                           const int* __restrict__ cv, const int* __restrict__ cc2,
                           float* __restrict__ out) {
    int idx = blockIdx.x * blockDim.x + threadIdx.x;
    if (idx >= NBb * 128) return;
    int b = idx >> 7, j = idx & 127;
    float v;
    if (j < 64) v = sv[b * 64 + j] / fmaxf((float)cv[b], 1.0f);
    else        v = sc[b * 64 + (j - 64)] / fmaxf((float)cc2[b], 1.0f);
    out[idx] = v;
}

// ==================================================================
extern "C" void kernel_launch(void* const* d_in, const int* in_sizes, int n_in,
                              void* d_out, int out_size, void* d_ws, size_t ws_size,
                              hipStream_t stream) {
    (void)in_sizes; (void)n_in; (void)out_size; (void)ws_size;
    const float* var_feats = (const float*)d_in[0];
    const float* cstr_feats = (const float*)d_in[1];
    const float* edge_attr = (const float*)d_in[2];
    const float* Wrel_v0 = (const float*)d_in[3];
    const float* brel_v0 = (const float*)d_in[4];
    const float* Wroot_v0 = (const float*)d_in[5];
    const float* Wrel_c0 = (const float*)d_in[6];
    const float* brel_c0 = (const float*)d_in[7];
    const float* Wroot_c0 = (const float*)d_in[8];
    const float* g_v0 = (const float*)d_in[9];
    const float* b_v0 = (const float*)d_in[10];
    const float* g_c0 = (const float*)d_in[11];
    const float* b_c0 = (const float*)d_in[12];
    const float* Wrel_v = (const float*)d_in[13];
    const float* brel_v = (const float*)d_in[14];
    const float* Wroot_v = (const float*)d_in[15];
    const float* Wrel_c = (const float*)d_in[16];
    const float* brel_c = (const float*)d_in[17];
    const float* Wroot_c = (const float*)d_in[18];
    const float* g_v = (const float*)d_in[19];
    const float* b_v = (const float*)d_in[20];
    const float* g_c = (const float*)d_in[21];
    const float* b_c = (const float*)d_in[22];
    const int* edge_index = (const int*)d_in[23];
    const int* var_batch = (const int*)d_in[24];
    const int* cstr_batch = (const int*)d_in[25];
    const int* src_c = edge_index;
    const int* dst_v = edge_index + NEn;
    float* out = (float*)d_out;

    // ---- workspace carve-out ----
    char* ws = (char*)d_ws;
    size_t off_b = 0;
    auto alloc = [&](size_t bytes) -> char* {
        char* p = ws + off_b;
        off_b = (off_b + bytes + 255) & ~(size_t)255;
        return p;
    };
    float* V0 = (float*)alloc((size_t)NVn * 64 * 4);
    float* V1 = (float*)alloc((size_t)NVn * 64 * 4);
    float* C0 = (float*)alloc((size_t)NCn * 64 * 4);
    float* C1 = (float*)alloc((size_t)NCn * 64 * 4);
    int* off_v = (int*)alloc((size_t)(NVn + 1) * 4);
    int* cur_v = (int*)alloc((size_t)NVn * 4);
    int* col_v = (int*)alloc((size_t)NEn * 4);
    float* w_v = (float*)alloc((size_t)NEn * 4);
    int* off_c = (int*)alloc((size_t)(NCn + 1) * 4);
    int* cur_c = (int*)alloc((size_t)NCn * 4);
    int* col_c = (int*)alloc((size_t)NEn * 4);
    float* w_c = (float*)alloc((size_t)NEn * 4);
    float* wsum_v = (float*)alloc((size_t)NVn * 4);
    float* wsum_c = (float*)alloc((size_t)NCn * 4);
    int* degzone = (int*)alloc((size_t)(NVn + NCn) * 4);
    int* degv = degzone;
    int* degc = degzone + NVn;
    int* bsum = (int*)alloc(1024 * 4);
    // zero-init zone (one memset): stats accums + pool sums + counts
    float* zzone = (float*)alloc(4992 * 4);
    float* accL0v = zzone;            // 32 (18 used)
    float* accL0c = zzone + 32;       // 8 (2 used)
    float* accLv[3], *accLc[3];
    for (int l = 0; l < 3; l++) { accLv[l] = zzone + 64 + l * 256; accLc[l] = zzone + 64 + l * 256 + 128; }
    float* pool_sv = zzone + 832;     // 2048
    float* pool_sc = zzone + 2880;    // 2048
    int* cnt_v = (int*)(zzone + 4928);  // 32
    int* cnt_c = (int*)(zzone + 4960);  // 32
    // folded weights
    float* Wr_v = (float*)alloc(4096 * 4);
    float* Wt_v = (float*)alloc(4096 * 4);
    float* b0_v = (float*)alloc(64 * 4);
    float* bw_v = (float*)alloc(64 * 4);
    float* Wr_c = (float*)alloc(4096 * 4);
    float* Wt_c = (float*)alloc(4096 * 4);
    float* b0_c = (float*)alloc(64 * 4);
    float* bw_c = (float*)alloc(64 * 4);
    // bf16 MFMA B-fragment buffers: [ks4][ct4][lane64][8 bf16]
    unsigned short* Bf_v = (unsigned short*)alloc(8192 * 2);
    unsigned short* Bf_c = (unsigned short*)alloc(8192 * 2);

    const float invNV = 1.0f / (float)NVn;
    const float invNC = 1.0f / (float)NCn;

    // ---- init ----
    hipMemsetAsync(degzone, 0, (size_t)(NVn + NCn) * 4, stream);
    hipMemsetAsync(zzone, 0, 4992 * 4, stream);

    // ---- build CSR both directions ----
    k_count_deg<<<2048, 256, 0, stream>>>(src_c, dst_v, degv, degc);
    int nbv = (NVn + 1023) / 1024;  // 196
    int nbc = (NCn + 1023) / 1024;  // 98
    k_scan_block<<<nbv, 256, 0, stream>>>(degv, NVn, bsum);
    k_scan_tops<<<1, 1024, 0, stream>>>(bsum, nbv);
    k_scan_final<<<nbv, 256, 0, stream>>>(degv, NVn, bsum, off_v, cur_v);
    k_scan_block<<<nbc, 256, 0, stream>>>(degc, NCn, bsum);
    k_scan_tops<<<1, 1024, 0, stream>>>(bsum, nbc);
    k_scan_final<<<nbc, 256, 0, stream>>>(degc, NCn, bsum, off_c, cur_c);
    k_fill<<<2048, 256, 0, stream>>>(dst_v, src_c, edge_attr, off_v, cur_v, col_v, w_v);
    k_fill<<<2048, 256, 0, stream>>>(src_c, dst_v, edge_attr, off_c, cur_c, col_c, w_c);
    k_wsum<<<784, 256, 0, stream>>>(off_v, w_v, wsum_v, NVn);
    k_wsum<<<392, 256, 0, stream>>>(off_c, w_c, wsum_c, NCn);

    // ---- layer 0 (var: 9 feats, cstr: 1 feat) ----
    k_stats_small<9><<<784, 256, 0, stream>>>(var_feats, NVn, accL0v);
    k_stats_small<1><<<392, 256, 0, stream>>>(cstr_feats, NCn, accL0c);
    k_fold<<<1, 256, 0, stream>>>(Wrel_v0, brel_v0, Wroot_v0,
                                 g_c0, b_c0, accL0c, invNC, 1,
                                 g_v0, b_v0, accL0v, invNV, 9,
                                 Wr_v, Wt_v, b0_v, bw_v, (unsigned short*)nullptr);
    k_fold<<<1, 256, 0, stream>>>(Wrel_c0, brel_c0, Wroot_c0,
                                 g_v0, b_v0, accL0v, invNV, 9,
                                 g_c0, b_c0, accL0c, invNC, 1,
                                 Wr_c, Wt_c, b0_c, bw_c, (unsigned short*)nullptr);
    k_agg1<<<784, 256, 0, stream>>>(cstr_feats, off_v, col_v, w_v, V0, NVn);       // [NV,1]
    k_agg<9><<<2048, 256, 0, stream>>>(var_feats, off_c, col_c, w_c, C0, NCn);     // [NC,9]
    k_gemm0<1, 9><<<(NVn * 64 + 255) / 256, 256, 0, stream>>>(V0, var_feats, wsum_v,
                                                              Wr_v, Wt_v, b0_v, bw_v, V1, NVn);
    k_gemm0<9, 1><<<(NCn * 64 + 255) / 256, 256, 0, stream>>>(C0, cstr_feats, wsum_c,
                                                              Wr_c, Wt_c, b0_c, bw_c, C1, NCn);

    // ---- layers 1..3 ----
    float* xv = V1; float* xc = C1; float* av = V0; float* ac = C0;
    for (int l = 0; l < 3; l++) {
        const float* Wrv = Wrel_v + (size_t)l * 4096;
        const float* brv = brel_v + (size_t)l * 64;
        const float* Wtv = Wroot_v + (size_t)l * 4096;
        const float* Wrc = Wrel_c + (size_t)l * 4096;
        const float* brc = brel_c + (size_t)l * 64;
        const float* Wtc = Wroot_c + (size_t)l * 4096;
        const float* gvl = g_v + (size_t)l * 64; const float* bvl = b_v + (size_t)l * 64;
        const float* gcl = g_c + (size_t)l * 64; const float* bcl = b_c + (size_t)l * 64;

        k_stats64<<<2048, 256, 0, stream>>>(xv, NVn, accLv[l]);
        k_stats64<<<2048, 256, 0, stream>>>(xc, NCn, accLc[l]);
        k_fold<<<1, 256, 0, stream>>>(Wrv, brv, Wtv,
                                     gcl, bcl, accLc[l], invNC, 64,
                                     gvl, bvl, accLv[l], invNV, 64,
                                     Wr_v, Wt_v, b0_v, bw_v, Bf_v);
        k_fold<<<1, 256, 0, stream>>>(Wrc, brc, Wtc,
                                     gvl, bvl, accLv[l], invNV, 64,
                                     gcl, bcl, accLc[l], invNC, 64,
                                     Wr_c, Wt_c, b0_c, bw_c, Bf_c);
        k_agg<64><<<2048, 256, 0, stream>>>(xc, off_v, col_v, w_v, av, NVn);
        k_agg<64><<<2048, 256, 0, stream>>>(xv, off_c, col_c, w_c, ac, NCn);
        k_gemm<<<(NVn + 63) / 64, 256, 0, stream>>>(av, xv, wsum_v, Bf_v, b0_v, bw_v, av, NVn);
        k_gemm<<<(NCn + 63) / 64, 256, 0, stream>>>(ac, xc, wsum_c, Bf_c, b0_c, bw_c, ac, NCn);
        // swap
        float* tv = xv; xv = av; av = tv;
        float* tcp = xc; xc = ac; ac = tcp;
    }

    // ---- pooling ----
    k_seg_count<<<(NVn + 255) / 256, 256, 0, stream>>>(var_batch, NVn, cnt_v);
    k_seg_count<<<(NCn + 255) / 256, 256, 0, stream>>>(cstr_batch, NCn, cnt_c);
    k_pool_accum<<<(NVn + 127) / 128, 256, 0, stream>>>(xv, var_batch, NVn, pool_sv);
    k_pool_accum<<<(NCn + 127) / 128, 256, 0, stream>>>(xc, cstr_batch, NCn, pool_sc);
    k_pool_div<<<(NBb * 128 + 255) / 256, 256, 0, stream>>>(pool_sv, pool_sc, cnt_v, cnt_c, out);
}

// Round 11
// 1166.278 us; speedup vs baseline: 1.1288x; 1.1288x over previous
//
#include <hip/hip_runtime.h>

// Problem constants (match reference setup_inputs)
constexpr int NVn = 200000;   // var nodes, 9 feats in
constexpr int NCn = 100000;   // cstr nodes, 1 feat in
constexpr int NEn = 1000000;  // edges
constexpr int NBb = 32;       // graphs
#define EPSf 1e-5f

typedef unsigned short u16;
typedef __attribute__((ext_vector_type(8))) short s8v;   // 8 bf16 (4 VGPRs)
typedef __attribute__((ext_vector_type(4))) float f4v;   // 4 f32 acc

// f32 -> bf16 bits, round-to-nearest-even
static __device__ __forceinline__ u16 f2b(float f) {
    union { float f; unsigned u; } x; x.f = f;
    return (u16)((x.u + 0x7FFFu + ((x.u >> 16) & 1u)) >> 16);
}
static __device__ __forceinline__ float b2f(u16 u) {
    union { unsigned u; float f; } x; x.u = ((unsigned)u) << 16; return x.f;
}

// load 8 consecutive f32, convert to bf16x8 fragment
static __device__ __forceinline__ s8v cvt8(const float* p) {
    float4 a = *(const float4*)p;
    float4 b = *(const float4*)(p + 4);
    s8v r;
    r[0] = (short)f2b(a.x); r[1] = (short)f2b(a.y); r[2] = (short)f2b(a.z); r[3] = (short)f2b(a.w);
    r[4] = (short)f2b(b.x); r[5] = (short)f2b(b.y); r[6] = (short)f2b(b.z); r[7] = (short)f2b(b.w);
    return r;
}

// store folded weight W[kg][h] (kg in 0..127, h in 0..63) into MFMA B-fragment order:
// fragment (ks=kg>>5, ct=h>>4), lane = ((kg>>3)&3)<<4 | (h&15), elem j = kg&7
static __device__ __forceinline__ void frag_store(u16* B, int kg, int h, float w) {
    int ks = kg >> 5, g = (kg >> 3) & 3, j = kg & 7, ct = h >> 4;
    int lane = (g << 4) | (h & 15);
    B[((((ks << 2) | ct) << 6) | lane) * 8 + j] = f2b(w);
}

// ---------------- degree count ----------------
__global__ __launch_bounds__(256) void k_count_deg(const int* __restrict__ src, const int* __restrict__ dst,
                            int* __restrict__ degv, int* __restrict__ degc) {
    for (int e = blockIdx.x * blockDim.x + threadIdx.x; e < NEn; e += gridDim.x * blockDim.x) {
        atomicAdd(&degv[dst[e]], 1);
        atomicAdd(&degc[src[e]], 1);
    }
}

// ---------------- exclusive scan (3 kernels, 1024 elems/block) ----------------
__global__ __launch_bounds__(256) void k_scan_block(const int* __restrict__ deg, int n, int* __restrict__ bsum) {
    __shared__ int s[256];
    int base = blockIdx.x * 1024;
    int t = threadIdx.x;
    int v = 0;
#pragma unroll
    for (int j = 0; j < 4; j++) { int idx = base + t * 4 + j; if (idx < n) v += deg[idx]; }
    s[t] = v; __syncthreads();
    for (int o = 128; o > 0; o >>= 1) { if (t < o) s[t] += s[t + o]; __syncthreads(); }
    if (t == 0) bsum[blockIdx.x] = s[0];
}

__global__ __launch_bounds__(1024) void k_scan_tops(int* bsum, int nb) {
    __shared__ int s[1024];
    int t = threadIdx.x;
    int v = (t < nb) ? bsum[t] : 0;
    s[t] = v; __syncthreads();
    for (int o = 1; o < 1024; o <<= 1) {
        int x = (t >= o) ? s[t - o] : 0; __syncthreads();
        s[t] += x; __syncthreads();
    }
    if (t < nb) bsum[t] = s[t] - v;  // exclusive
}

__global__ __launch_bounds__(256) void k_scan_final(const int* __restrict__ deg, int n, const int* __restrict__ bsum,
                             int* __restrict__ off, int* __restrict__ cur) {
    __shared__ int s[256];
    int base = blockIdx.x * 1024, t = threadIdx.x;
    int d[4], loc[4], sum = 0;
#pragma unroll
    for (int j = 0; j < 4; j++) {
        int idx = base + t * 4 + j;
        d[j] = (idx < n) ? deg[idx] : 0;
        loc[j] = sum; sum += d[j];
    }
    s[t] = sum; __syncthreads();
    int v = sum;
    for (int o = 1; o < 256; o <<= 1) {
        int x = (t >= o) ? s[t - o] : 0; __syncthreads();
        s[t] += x; __syncthreads();
    }
    int texcl = s[t] - v + bsum[blockIdx.x];
#pragma unroll
    for (int j = 0; j < 4; j++) {
        int idx = base + t * 4 + j;
        if (idx < n) {
            int o2 = texcl + loc[j];
            off[idx] = o2; cur[idx] = o2;
            if (idx == n - 1) off[n] = o2 + d[j];
        }
    }
}

// ---------------- CSR fill (w = ew / deg) ----------------
__global__ __launch_bounds__(256) void k_fill(const int* __restrict__ key, const int* __restrict__ other,
                       const float* __restrict__ ew, const int* __restrict__ off,
                       int* __restrict__ cur, int* __restrict__ col, float* __restrict__ w) {
    for (int e = blockIdx.x * blockDim.x + threadIdx.x; e < NEn; e += gridDim.x * blockDim.x) {
        int d = key[e];
        int p = atomicAdd(&cur[d], 1);
        col[p] = other[e];
        float invd = 1.0f / (float)(off[d + 1] - off[d]);
        w[p] = ew[e] * invd;
    }
}

__global__ __launch_bounds__(256) void k_wsum(const int* __restrict__ off, const float* __restrict__ w,
                       float* __restrict__ ws, int n) {
    for (int i = blockIdx.x * blockDim.x + threadIdx.x; i < n; i += gridDim.x * blockDim.x) {
        int s = off[i], e = off[i + 1]; float t = 0.f;
        for (int j = s; j < e; j++) t += w[j];
        ws[i] = t;
    }
}

// ---------------- BN column stats (bf16 input) ----------------
__global__ __launch_bounds__(256) void k_stats64b(const u16* __restrict__ x, int n, float* __restrict__ acc) {
    int c = threadIdx.x & 63, r4 = threadIdx.x >> 6;
    float s = 0.f, q = 0.f;
    for (int i = blockIdx.x * 4 + r4; i < n; i += gridDim.x * 4) {
        float v = b2f(x[(size_t)i * 64 + c]); s += v; q = fmaf(v, v, q);
    }
    __shared__ float ls[512];
    ls[threadIdx.x] = s; ls[256 + threadIdx.x] = q;
    __syncthreads();
    if (r4 == 0) {
        atomicAdd(&acc[c], ls[c] + ls[c + 64] + ls[c + 128] + ls[c + 192]);
        atomicAdd(&acc[64 + c], ls[256 + c] + ls[256 + c + 64] + ls[256 + c + 128] + ls[256 + c + 192]);
    }
}

// f32 input, small D: 1 row/thread, wave shuffle-reduce, 2D atomics/block
template <int D>
__global__ __launch_bounds__(256) void k_stats_small(const float* __restrict__ x, int n, float* __restrict__ acc) {
    float s[D], q[D];
#pragma unroll
    for (int k = 0; k < D; k++) { s[k] = 0.f; q[k] = 0.f; }
    for (int i = blockIdx.x * blockDim.x + threadIdx.x; i < n; i += gridDim.x * blockDim.x) {
#pragma unroll
        for (int k = 0; k < D; k++) { float v = x[(size_t)i * D + k]; s[k] += v; q[k] = fmaf(v, v, q[k]); }
    }
#pragma unroll
    for (int k = 0; k < D; k++) {
#pragma unroll
        for (int o = 32; o > 0; o >>= 1) {
            s[k] += __shfl_down(s[k], o);
            q[k] += __shfl_down(q[k], o);
        }
    }
    __shared__ float ls[4][2 * D];
    int lane = threadIdx.x & 63, wv = threadIdx.x >> 6;
    if (lane == 0) {
#pragma unroll
        for (int k = 0; k < D; k++) { ls[wv][k] = s[k]; ls[wv][D + k] = q[k]; }
    }
    __syncthreads();
    int t = threadIdx.x;
    if (t < 2 * D) atomicAdd(&acc[t], ls[0][t] + ls[1][t] + ls[2][t] + ls[3][t]);
}

// ---------------- fold BN into weights (parallel: 256 thr, 4 waves split k-range) ----------
__global__ __launch_bounds__(256) void k_fold(const float* __restrict__ Wrel, const float* __restrict__ brel,
                       const float* __restrict__ Wroot,
                       const float* __restrict__ gs, const float* __restrict__ bs,
                       const float* __restrict__ accs, float invNs, int DSv,
                       const float* __restrict__ gd, const float* __restrict__ bd,
                       const float* __restrict__ accd, float invNd, int DDv,
                       float* __restrict__ Wr_o, float* __restrict__ Wt_o,
                       float* __restrict__ b0_o, float* __restrict__ bw_o,
                       u16* __restrict__ Bfrag) {
    __shared__ float sa[128], sbe[128];
    __shared__ float rb0[4][64], rbw[4][64];
    int t = threadIdx.x;
    int total = DSv + DDv;
    for (int k = t; k < total; k += 256) {
        bool isrc = k < DSv;
        int kk = isrc ? k : k - DSv;
        const float* acc = isrc ? accs : accd;
        float invN = isrc ? invNs : invNd;
        int D = isrc ? DSv : DDv;
        float g = isrc ? gs[kk] : gd[kk];
        float b = isrc ? bs[kk] : bd[kk];
        float m = acc[kk] * invN;
        float var = acc[D + kk] * invN - m * m;
        float a = g * rsqrtf(var + EPSf);
        sa[k] = a; sbe[k] = b - m * a;
    }
    __syncthreads();
    int h = t & 63, q = t >> 6;
    float bw = 0.f, b0 = 0.f;
    for (int k = q; k < DSv; k += 4) {
        float wv = Wrel[k * 64 + h];
        float wf = sa[k] * wv;
        Wr_o[k * 64 + h] = wf;
        bw = fmaf(sbe[k], wv, bw);
        if (Bfrag) frag_store(Bfrag, k, h, wf);
    }
    for (int k = q; k < DDv; k += 4) {
        float wv = Wroot[k * 64 + h];
        float wf = sa[DSv + k] * wv;
        Wt_o[k * 64 + h] = wf;
        b0 = fmaf(sbe[DSv + k], wv, b0);
        if (Bfrag) frag_store(Bfrag, 64 + k, h, wf);
    }
    rb0[q][h] = b0; rbw[q][h] = bw;
    __syncthreads();
    if (q == 0) {
        b0_o[h] = brel[h] + rb0[0][h] + rb0[1][h] + rb0[2][h] + rb0[3][h];
        bw_o[h] = rbw[0][h] + rbw[1][h] + rbw[2][h] + rbw[3][h];
    }
}

// ---------------- layer-0 helpers ----------------
// aggregation from CSR, small DS, f32 in/out
template <int DS>
__global__ __launch_bounds__(256) void k_agg(const float* __restrict__ xs, const int* __restrict__ off,
                      const int* __restrict__ col, const float* __restrict__ w,
                      float* __restrict__ agg, int n) {
    int lane = threadIdx.x & 63;
    int wid = (blockIdx.x * blockDim.x + threadIdx.x) >> 6;
    int nw = (gridDim.x * blockDim.x) >> 6;
    for (int i = wid; i < n; i += nw) {
        int s = off[i], e = off[i + 1];
        if (lane < DS) {
            float a0 = 0.f, a1 = 0.f, a2 = 0.f, a3 = 0.f;
            int j = s;
            for (; j + 3 < e; j += 4) {
                int c0 = col[j], c1 = col[j + 1], c2 = col[j + 2], c3 = col[j + 3];
                float w0 = w[j], w1 = w[j + 1], w2 = w[j + 2], w3 = w[j + 3];
                a0 = fmaf(w0, xs[(size_t)c0 * DS + lane], a0);
                a1 = fmaf(w1, xs[(size_t)c1 * DS + lane], a1);
                a2 = fmaf(w2, xs[(size_t)c2 * DS + lane], a2);
                a3 = fmaf(w3, xs[(size_t)c3 * DS + lane], a3);
            }
            for (; j < e; j++) a0 = fmaf(w[j], xs[(size_t)col[j] * DS + lane], a0);
            agg[(size_t)i * DS + lane] = (a0 + a1) + (a2 + a3);
        }
    }
}

__global__ __launch_bounds__(256) void k_agg1(const float* __restrict__ xs, const int* __restrict__ off,
                       const int* __restrict__ col, const float* __restrict__ w,
                       float* __restrict__ agg, int n) {
    for (int i = blockIdx.x * blockDim.x + threadIdx.x; i < n; i += gridDim.x * blockDim.x) {
        int s = off[i], e = off[i + 1]; float a = 0.f;
        for (int j = s; j < e; j++) a = fmaf(w[j], xs[col[j]], a);
        agg[i] = a;
    }
}

// layer-0 small-K GEMM: thread per (node, h); bf16 output
template <int KS, int KD>
__global__ __launch_bounds__(256) void k_gemm0(const float* __restrict__ aggs, const float* __restrict__ xd,
                        const float* __restrict__ wsum,
                        const float* __restrict__ Wr, const float* __restrict__ Wt,
                        const float* __restrict__ b0, const float* __restrict__ bw,
                        u16* __restrict__ out, int n) {
    int idx = blockIdx.x * blockDim.x + threadIdx.x;
    int i = idx >> 6, h = idx & 63;
    if (i >= n) return;
    float acc = b0[h] + wsum[i] * bw[h];
#pragma unroll
    for (int k = 0; k < KS; k++) acc = fmaf(aggs[i * KS + k], Wr[k * 64 + h], acc);
#pragma unroll
    for (int k = 0; k < KD; k++) acc = fmaf(xd[i * KD + k], Wt[k * 64 + h], acc);
    out[(size_t)i * 64 + h] = f2b(fmaxf(acc, 0.0f));
}

// ---------------- FUSED layer: agg (gather) + MFMA GEMM + epilogue + next-layer BN stats ----
// Round-9 fusion: kills the 51 MB agg round-trip per layer side, reads/writes features
// as bf16 (halves gather + root + store traffic), and folds next-layer column stats
// into the epilogue (kills standalone stats pass).
// Block = 256 thr = 4 waves; wave wv owns rows [blk*64 + wv*16, +16).
// Phase 1: per row, all 64 lanes (lane=feature) gather-aggregate; bf16 result to
//          per-wave LDS [16][72] (72-short stride: 16B-aligned rows, conflict-benign).
// Phase 2: 16 x mfma_f32_16x16x32_bf16; A(agg) from LDS, A(root) from global bf16.
// Phase 3: bias + wsum*bw + relu -> bf16 store; column sum/sumsq partials via
//          shfl_xor(16,32) + LDS + 128 atomics/block (skipped when statacc==null).
__global__ __launch_bounds__(256, 2) void k_layer(
        const u16* __restrict__ xs, const u16* __restrict__ xr,
        const int* __restrict__ off, const int* __restrict__ col, const float* __restrict__ w,
        const float* __restrict__ wsum, const u16* __restrict__ Bfrag,
        const float* __restrict__ b0v, const float* __restrict__ bwv,
        u16* __restrict__ out, float* __restrict__ statacc, int n) {
    __shared__ __align__(16) u16 lagg[4][16][72];
    __shared__ float lstat[4][2][64];
    int t = threadIdx.x;
    int wv = t >> 6, l = t & 63;
    int lrow = l & 15, lkg = l >> 4;
    int base = blockIdx.x * 64 + wv * 16;
    // phase 1: aggregate
    for (int r = 0; r < 16; ++r) {
        int row = base + r;
        float a0 = 0.f, a1 = 0.f, a2 = 0.f, a3 = 0.f;
        if (row < n) {
            int s = off[row], e = off[row + 1];
            int j = s;
            for (; j + 3 < e; j += 4) {
                int c0 = col[j], c1 = col[j + 1], c2 = col[j + 2], c3 = col[j + 3];
                float w0 = w[j], w1 = w[j + 1], w2 = w[j + 2], w3 = w[j + 3];
                a0 = fmaf(w0, b2f(xs[(size_t)c0 * 64 + l]), a0);
                a1 = fmaf(w1, b2f(xs[(size_t)c1 * 64 + l]), a1);
                a2 = fmaf(w2, b2f(xs[(size_t)c2 * 64 + l]), a2);
                a3 = fmaf(w3, b2f(xs[(size_t)c3 * 64 + l]), a3);
            }
            for (; j < e; ++j) a0 = fmaf(w[j], b2f(xs[(size_t)col[j] * 64 + l]), a0);
        }
        lagg[wv][r][l] = f2b((a0 + a1) + (a2 + a3));
    }
    // phase 2: MFMA (per-wave LDS region: wave-synchronous, no barrier needed)
    const u16* Bl = Bfrag + l * 8;
    f4v acc0 = {0.f, 0.f, 0.f, 0.f};
    f4v acc1 = acc0, acc2 = acc0, acc3 = acc0;
#define LSTEP(ks, APTR)                                                       \
    {                                                                         \
        s8v a = *(const s8v*)(APTR);                                          \
        s8v f0 = *(const s8v*)(Bl + ((ks) * 4 + 0) * 512);                    \
        s8v f1 = *(const s8v*)(Bl + ((ks) * 4 + 1) * 512);                    \
        s8v f2 = *(const s8v*)(Bl + ((ks) * 4 + 2) * 512);                    \
        s8v f3 = *(const s8v*)(Bl + ((ks) * 4 + 3) * 512);                    \
        acc0 = __builtin_amdgcn_mfma_f32_16x16x32_bf16(a, f0, acc0, 0, 0, 0); \
        acc1 = __builtin_amdgcn_mfma_f32_16x16x32_bf16(a, f1, acc1, 0, 0, 0); \
        acc2 = __builtin_amdgcn_mfma_f32_16x16x32_bf16(a, f2, acc2, 0, 0, 0); \
        acc3 = __builtin_amdgcn_mfma_f32_16x16x32_bf16(a, f3, acc3, 0, 0, 0); \
    }
    LSTEP(0, &lagg[wv][lrow][lkg * 8])
    LSTEP(1, &lagg[wv][lrow][32 + lkg * 8])
    int arow = base + lrow; if (arow >= n) arow = 0;
    const u16* xp = xr + (size_t)arow * 64 + lkg * 8;
    LSTEP(2, xp)
    LSTEP(3, xp + 32)
#undef LSTEP
    // phase 3: epilogue + stats
    int orow = base + lkg * 4;
    bool ok0 = orow + 0 < n, ok1 = orow + 1 < n, ok2 = orow + 2 < n, ok3 = orow + 3 < n;
    float ws0 = ok0 ? wsum[orow + 0] : 0.f;
    float ws1 = ok1 ? wsum[orow + 1] : 0.f;
    float ws2 = ok2 ? wsum[orow + 2] : 0.f;
    float ws3 = ok3 ? wsum[orow + 3] : 0.f;
#define EPI(ACC, ct)                                                          \
    {                                                                         \
        int c = (ct) * 16 + lrow;                                             \
        float bb = b0v[c], wb = bwv[c];                                       \
        float v0 = ok0 ? fmaxf(ACC[0] + bb + ws0 * wb, 0.f) : 0.f;            \
        float v1 = ok1 ? fmaxf(ACC[1] + bb + ws1 * wb, 0.f) : 0.f;            \
        float v2 = ok2 ? fmaxf(ACC[2] + bb + ws2 * wb, 0.f) : 0.f;            \
        float v3 = ok3 ? fmaxf(ACC[3] + bb + ws3 * wb, 0.f) : 0.f;            \
        if (ok0) out[(size_t)(orow + 0) * 64 + c] = f2b(v0);                  \
        if (ok1) out[(size_t)(orow + 1) * 64 + c] = f2b(v1);                  \
        if (ok2) out[(size_t)(orow + 2) * 64 + c] = f2b(v2);                  \
        if (ok3) out[(size_t)(orow + 3) * 64 + c] = f2b(v3);                  \
        if (statacc) {                                                        \
            float sv = (v0 + v1) + (v2 + v3);                                 \
            float qv = fmaf(v0, v0, fmaf(v1, v1, fmaf(v2, v2, v3 * v3)));     \
            sv += __shfl_xor(sv, 16); sv += __shfl_xor(sv, 32);               \
            qv += __shfl_xor(qv, 16); qv += __shfl_xor(qv, 32);               \
            if (lkg == 0) { lstat[wv][0][c] = sv; lstat[wv][1][c] = qv; }     \
        }                                                                     \
    }
    EPI(acc0, 0)
    EPI(acc1, 1)
    EPI(acc2, 2)
    EPI(acc3, 3)
#undef EPI
    if (statacc) {
        __syncthreads();
        if (t < 128) {
            int c = t & 63, p = t >> 6;
            atomicAdd(&statacc[p * 64 + c],
                      lstat[0][p][c] + lstat[1][p][c] + lstat[2][p][c] + lstat[3][p][c]);
        }
    }
}

// ---------------- pooling ----------------
__global__ __launch_bounds__(256) void k_seg_count(const int* __restrict__ batch, int n, int* __restrict__ cnt) {
    int i = blockIdx.x * blockDim.x + threadIdx.x;
    if (i >= n) return;
    int lane = threadIdx.x & 63;
    int b = batch[i];
    int bprev = __shfl_up(b, 1);
    bool head = (lane == 0) || (b != bprev);
    unsigned long long hb = __ballot(head);
    if (head) {
        unsigned long long mask = (lane == 63) ? 0ULL : (hb >> (lane + 1));
        int wstart = i - lane;
        int nvalid = min(64, n - wstart);
        int end = (mask == 0ULL) ? nvalid : (lane + 1 + __ffsll((long long)mask) - 1);
        atomicAdd(&cnt[b], end - lane);
    }
}

// bf16 features; 128 rows/block (32/walker); batch sorted -> ~1 run/walker
__global__ __launch_bounds__(256) void k_pool_accum(const u16* __restrict__ x, const int* __restrict__ batch,
                             int n, float* __restrict__ sums) {
    int c = threadIdx.x & 63, r4 = threadIdx.x >> 6;
    int base = blockIdx.x * 128 + r4 * 32;
    int end = min(n, base + 32);
    float acc = 0.f; int cur = -1;
    for (int i = base; i < end; ++i) {
        int b = batch[i];
        if (b != cur) {
            if (cur >= 0) atomicAdd(&sums[cur * 64 + c], acc);
            acc = 0.f; cur = b;
        }
        acc += b2f(x[(size_t)i * 64 + c]);
    }
    if (cur >= 0) atomicAdd(&sums[cur * 64 + c], acc);
}

__global__ __launch_bounds__(256) void k_pool_div(const float* __restrict__ sv, const float* __restrict__ sc,
                           const int* __restrict__ cv, const int* __restrict__ cc2,
                           float* __restrict__ out) {
    int idx = blockIdx.x * blockDim.x + threadIdx.x;
    if (idx >= NBb * 128) return;
    int b = idx >> 7, j = idx & 127;
    float v;
    if (j < 64) v = sv[b * 64 + j] / fmaxf((float)cv[b], 1.0f);
    else        v = sc[b * 64 + (j - 64)] / fmaxf((float)cc2[b], 1.0f);
    out[idx] = v;
}

// ==================================================================
extern "C" void kernel_launch(void* const* d_in, const int* in_sizes, int n_in,
                              void* d_out, int out_size, void* d_ws, size_t ws_size,
                              hipStream_t stream) {
    (void)in_sizes; (void)n_in; (void)out_size; (void)ws_size;
    const float* var_feats = (const float*)d_in[0];
    const float* cstr_feats = (const float*)d_in[1];
    const float* edge_attr = (const float*)d_in[2];
    const float* Wrel_v0 = (const float*)d_in[3];
    const float* brel_v0 = (const float*)d_in[4];
    const float* Wroot_v0 = (const float*)d_in[5];
    const float* Wrel_c0 = (const float*)d_in[6];
    const float* brel_c0 = (const float*)d_in[7];
    const float* Wroot_c0 = (const float*)d_in[8];
    const float* g_v0 = (const float*)d_in[9];
    const float* b_v0 = (const float*)d_in[10];
    const float* g_c0 = (const float*)d_in[11];
    const float* b_c0 = (const float*)d_in[12];
    const float* Wrel_v = (const float*)d_in[13];
    const float* brel_v = (const float*)d_in[14];
    const float* Wroot_v = (const float*)d_in[15];
    const float* Wrel_c = (const float*)d_in[16];
    const float* brel_c = (const float*)d_in[17];
    const float* Wroot_c = (const float*)d_in[18];
    const float* g_v = (const float*)d_in[19];
    const float* b_v = (const float*)d_in[20];
    const float* g_c = (const float*)d_in[21];
    const float* b_c = (const float*)d_in[22];
    const int* edge_index = (const int*)d_in[23];
    const int* var_batch = (const int*)d_in[24];
    const int* cstr_batch = (const int*)d_in[25];
    const int* src_c = edge_index;
    const int* dst_v = edge_index + NEn;
    float* out = (float*)d_out;

    // ---- workspace carve-out ----
    char* ws = (char*)d_ws;
    size_t off_b = 0;
    auto alloc = [&](size_t bytes) -> char* {
        char* p = ws + off_b;
        off_b = (off_b + bytes + 255) & ~(size_t)255;
        return p;
    };
    // bf16 feature ping-pong buffers
    u16* Vb[2] = { (u16*)alloc((size_t)NVn * 64 * 2), (u16*)alloc((size_t)NVn * 64 * 2) };
    u16* Cb[2] = { (u16*)alloc((size_t)NCn * 64 * 2), (u16*)alloc((size_t)NCn * 64 * 2) };
    // layer-0 f32 agg scratch (small D)
    float* aggV0 = (float*)alloc((size_t)NVn * 4);        // [NV,1]
    float* aggC0 = (float*)alloc((size_t)NCn * 9 * 4);    // [NC,9]
    int* off_v = (int*)alloc((size_t)(NVn + 1) * 4);
    int* cur_v = (int*)alloc((size_t)NVn * 4);
    int* col_v = (int*)alloc((size_t)NEn * 4);
    float* w_v = (float*)alloc((size_t)NEn * 4);
    int* off_c = (int*)alloc((size_t)(NCn + 1) * 4);
    int* cur_c = (int*)alloc((size_t)NCn * 4);
    int* col_c = (int*)alloc((size_t)NEn * 4);
    float* w_c = (float*)alloc((size_t)NEn * 4);
    float* wsum_v = (float*)alloc((size_t)NVn * 4);
    float* wsum_c = (float*)alloc((size_t)NCn * 4);
    int* degzone = (int*)alloc((size_t)(NVn + NCn) * 4);
    int* degv = degzone;
    int* degc = degzone + NVn;
    int* bsum = (int*)alloc(1024 * 4);
    // zero-init zone (one memset): stats accums + pool sums + counts
    float* zzone = (float*)alloc(4992 * 4);
    float* accL0v = zzone;            // 32 (18 used)
    float* accL0c = zzone + 32;       // 8 (2 used)
    float* accLv[3], *accLc[3];
    for (int l = 0; l < 3; l++) { accLv[l] = zzone + 64 + l * 256; accLc[l] = zzone + 64 + l * 256 + 128; }
    float* pool_sv = zzone + 832;     // 2048
    float* pool_sc = zzone + 2880;    // 2048
    int* cnt_v = (int*)(zzone + 4928);  // 32
    int* cnt_c = (int*)(zzone + 4960);  // 32
    // folded weights
    float* Wr_v = (float*)alloc(4096 * 4);
    float* Wt_v = (float*)alloc(4096 * 4);
    float* b0_v = (float*)alloc(64 * 4);
    float* bw_v = (float*)alloc(64 * 4);
    float* Wr_c = (float*)alloc(4096 * 4);
    float* Wt_c = (float*)alloc(4096 * 4);
    float* b0_c = (float*)alloc(64 * 4);
    float* bw_c = (float*)alloc(64 * 4);
    // bf16 MFMA B-fragment buffers: [ks4][ct4][lane64][8 bf16]
    u16* Bf_v = (u16*)alloc(8192 * 2);
    u16* Bf_c = (u16*)alloc(8192 * 2);

    const float invNV = 1.0f / (float)NVn;
    const float invNC = 1.0f / (float)NCn;

    // ---- init ----
    hipMemsetAsync(degzone, 0, (size_t)(NVn + NCn) * 4, stream);
    hipMemsetAsync(zzone, 0, 4992 * 4, stream);

    // ---- build CSR both directions ----
    k_count_deg<<<2048, 256, 0, stream>>>(src_c, dst_v, degv, degc);
    int nbv = (NVn + 1023) / 1024;  // 196
    int nbc = (NCn + 1023) / 1024;  // 98
    k_scan_block<<<nbv, 256, 0, stream>>>(degv, NVn, bsum);
    k_scan_tops<<<1, 1024, 0, stream>>>(bsum, nbv);
    k_scan_final<<<nbv, 256, 0, stream>>>(degv, NVn, bsum, off_v, cur_v);
    k_scan_block<<<nbc, 256, 0, stream>>>(degc, NCn, bsum);
    k_scan_tops<<<1, 1024, 0, stream>>>(bsum, nbc);
    k_scan_final<<<nbc, 256, 0, stream>>>(degc, NCn, bsum, off_c, cur_c);
    k_fill<<<2048, 256, 0, stream>>>(dst_v, src_c, edge_attr, off_v, cur_v, col_v, w_v);
    k_fill<<<2048, 256, 0, stream>>>(src_c, dst_v, edge_attr, off_c, cur_c, col_c, w_c);
    k_wsum<<<784, 256, 0, stream>>>(off_v, w_v, wsum_v, NVn);
    k_wsum<<<392, 256, 0, stream>>>(off_c, w_c, wsum_c, NCn);

    // ---- layer 0 (var: 9 feats, cstr: 1 feat) ----
    k_stats_small<9><<<784, 256, 0, stream>>>(var_feats, NVn, accL0v);
    k_stats_small<1><<<392, 256, 0, stream>>>(cstr_feats, NCn, accL0c);
    k_fold<<<1, 256, 0, stream>>>(Wrel_v0, brel_v0, Wroot_v0,
                                 g_c0, b_c0, accL0c, invNC, 1,
                                 g_v0, b_v0, accL0v, invNV, 9,
                                 Wr_v, Wt_v, b0_v, bw_v, (u16*)nullptr);
    k_fold<<<1, 256, 0, stream>>>(Wrel_c0, brel_c0, Wroot_c0,
                                 g_v0, b_v0, accL0v, invNV, 9,
                                 g_c0, b_c0, accL0c, invNC, 1,
                                 Wr_c, Wt_c, b0_c, bw_c, (u16*)nullptr);
    k_agg1<<<784, 256, 0, stream>>>(cstr_feats, off_v, col_v, w_v, aggV0, NVn);       // [NV,1]
    k_agg<9><<<2048, 256, 0, stream>>>(var_feats, off_c, col_c, w_c, aggC0, NCn);     // [NC,9]
    k_gemm0<1, 9><<<(NVn * 64 + 255) / 256, 256, 0, stream>>>(aggV0, var_feats, wsum_v,
                                                              Wr_v, Wt_v, b0_v, bw_v, Vb[0], NVn);
    k_gemm0<9, 1><<<(NCn * 64 + 255) / 256, 256, 0, stream>>>(aggC0, cstr_feats, wsum_c,
                                                              Wr_c, Wt_c, b0_c, bw_c, Cb[0], NCn);
    k_stats64b<<<2048, 256, 0, stream>>>(Vb[0], NVn, accLv[0]);
    k_stats64b<<<2048, 256, 0, stream>>>(Cb[0], NCn, accLc[0]);

    // ---- layers 1..3 (fused agg+GEMM+stats) ----
    int cur = 0;
    for (int l = 0; l < 3; l++) {
        const float* Wrv = Wrel_v + (size_t)l * 4096;
        const float* brv = brel_v + (size_t)l * 64;
        const float* Wtv = Wroot_v + (size_t)l * 4096;
        const float* Wrc = Wrel_c + (size_t)l * 4096;
        const float* brc = brel_c + (size_t)l * 64;
        const float* Wtc = Wroot_c + (size_t)l * 4096;
        const float* gvl = g_v + (size_t)l * 64; const float* bvl = b_v + (size_t)l * 64;
        const float* gcl = g_c + (size_t)l * 64; const float* bcl = b_c + (size_t)l * 64;

        k_fold<<<1, 256, 0, stream>>>(Wrv, brv, Wtv,
                                     gcl, bcl, accLc[l], invNC, 64,
                                     gvl, bvl, accLv[l], invNV, 64,
                                     Wr_v, Wt_v, b0_v, bw_v, Bf_v);
        k_fold<<<1, 256, 0, stream>>>(Wrc, brc, Wtc,
                                     gvl, bvl, accLv[l], invNV, 64,
                                     gcl, bcl, accLc[l], invNC, 64,
                                     Wr_c, Wt_c, b0_c, bw_c, Bf_c);
        int nxt = cur ^ 1;
        float* sv = (l < 2) ? accLv[l + 1] : (float*)nullptr;
        float* sc = (l < 2) ? accLc[l + 1] : (float*)nullptr;
        k_layer<<<(NVn + 63) / 64, 256, 0, stream>>>(Cb[cur], Vb[cur], off_v, col_v, w_v,
                                                     wsum_v, Bf_v, b0_v, bw_v, Vb[nxt], sv, NVn);
        k_layer<<<(NCn + 63) / 64, 256, 0, stream>>>(Vb[cur], Cb[cur], off_c, col_c, w_c,
                                                     wsum_c, Bf_c, b0_c, bw_c, Cb[nxt], sc, NCn);
        cur = nxt;
    }

    // ---- pooling ----
    k_seg_count<<<(NVn + 255) / 256, 256, 0, stream>>>(var_batch, NVn, cnt_v);
    k_seg_count<<<(NCn + 255) / 256, 256, 0, stream>>>(cstr_batch, NCn, cnt_c);
    k_pool_accum<<<(NVn + 127) / 128, 256, 0, stream>>>(Vb[cur], var_batch, NVn, pool_sv);
    k_pool_accum<<<(NCn + 127) / 128, 256, 0, stream>>>(Cb[cur], cstr_batch, NCn, pool_sc);
    k_pool_div<<<(NBb * 128 + 255) / 256, 256, 0, stream>>>(pool_sv, pool_sc, cnt_v, cnt_c, out);
}

// Round 12
// 1063.231 us; speedup vs baseline: 1.2382x; 1.0969x over previous
//
#include <hip/hip_runtime.h>

// Problem constants (match reference setup_inputs)
constexpr int NVn = 200000;   // var nodes, 9 feats in
constexpr int NCn = 100000;   // cstr nodes, 1 feat in
constexpr int NEn = 1000000;  // edges
constexpr int NBb = 32;       // graphs
#define EPSf 1e-5f

typedef unsigned short u16;
typedef __attribute__((ext_vector_type(8))) short s8v;   // 8 bf16 (4 VGPRs)
typedef __attribute__((ext_vector_type(4))) float f4v;   // 4 f32 acc

// f32 -> bf16 bits, round-to-nearest-even
static __device__ __forceinline__ u16 f2b(float f) {
    union { float f; unsigned u; } x; x.f = f;
    return (u16)((x.u + 0x7FFFu + ((x.u >> 16) & 1u)) >> 16);
}
static __device__ __forceinline__ float b2f(u16 u) {
    union { unsigned u; float f; } x; x.u = ((unsigned)u) << 16; return x.f;
}

// store folded weight W[kg][h] (kg in 0..127, h in 0..63) into MFMA B-fragment order:
// fragment (ks=kg>>5, ct=h>>4), lane = ((kg>>3)&3)<<4 | (h&15), elem j = kg&7
static __device__ __forceinline__ void frag_store(u16* B, int kg, int h, float w) {
    int ks = kg >> 5, g = (kg >> 3) & 3, j = kg & 7, ct = h >> 4;
    int lane = (g << 4) | (h & 15);
    B[((((ks << 2) | ct) << 6) | lane) * 8 + j] = f2b(w);
}

// ---------------- degree count ----------------
__global__ __launch_bounds__(256) void k_count_deg(const int* __restrict__ src, const int* __restrict__ dst,
                            int* __restrict__ degv, int* __restrict__ degc) {
    for (int e = blockIdx.x * blockDim.x + threadIdx.x; e < NEn; e += gridDim.x * blockDim.x) {
        atomicAdd(&degv[dst[e]], 1);
        atomicAdd(&degc[src[e]], 1);
    }
}

// ---------------- exclusive scan (3 kernels, 1024 elems/block) ----------------
__global__ __launch_bounds__(256) void k_scan_block(const int* __restrict__ deg, int n, int* __restrict__ bsum) {
    __shared__ int s[256];
    int base = blockIdx.x * 1024;
    int t = threadIdx.x;
    int v = 0;
#pragma unroll
    for (int j = 0; j < 4; j++) { int idx = base + t * 4 + j; if (idx < n) v += deg[idx]; }
    s[t] = v; __syncthreads();
    for (int o = 128; o > 0; o >>= 1) { if (t < o) s[t] += s[t + o]; __syncthreads(); }
    if (t == 0) bsum[blockIdx.x] = s[0];
}

__global__ __launch_bounds__(1024) void k_scan_tops(int* bsum, int nb) {
    __shared__ int s[1024];
    int t = threadIdx.x;
    int v = (t < nb) ? bsum[t] : 0;
    s[t] = v; __syncthreads();
    for (int o = 1; o < 1024; o <<= 1) {
        int x = (t >= o) ? s[t - o] : 0; __syncthreads();
        s[t] += x; __syncthreads();
    }
    if (t < nb) bsum[t] = s[t] - v;  // exclusive
}

__global__ __launch_bounds__(256) void k_scan_final(const int* __restrict__ deg, int n, const int* __restrict__ bsum,
                             int* __restrict__ off, int* __restrict__ cur) {
    __shared__ int s[256];
    int base = blockIdx.x * 1024, t = threadIdx.x;
    int d[4], loc[4], sum = 0;
#pragma unroll
    for (int j = 0; j < 4; j++) {
        int idx = base + t * 4 + j;
        d[j] = (idx < n) ? deg[idx] : 0;
        loc[j] = sum; sum += d[j];
    }
    s[t] = sum; __syncthreads();
    int v = sum;
    for (int o = 1; o < 256; o <<= 1) {
        int x = (t >= o) ? s[t - o] : 0; __syncthreads();
        s[t] += x; __syncthreads();
    }
    int texcl = s[t] - v + bsum[blockIdx.x];
#pragma unroll
    for (int j = 0; j < 4; j++) {
        int idx = base + t * 4 + j;
        if (idx < n) {
            int o2 = texcl + loc[j];
            off[idx] = o2; cur[idx] = o2;
            if (idx == n - 1) off[n] = o2 + d[j];
        }
    }
}

// ---------------- CSR fill (w = ew / deg) ----------------
__global__ __launch_bounds__(256) void k_fill(const int* __restrict__ key, const int* __restrict__ other,
                       const float* __restrict__ ew, const int* __restrict__ off,
                       int* __restrict__ cur, int* __restrict__ col, float* __restrict__ w) {
    for (int e = blockIdx.x * blockDim.x + threadIdx.x; e < NEn; e += gridDim.x * blockDim.x) {
        int d = key[e];
        int p = atomicAdd(&cur[d], 1);
        col[p] = other[e];
        float invd = 1.0f / (float)(off[d + 1] - off[d]);
        w[p] = ew[e] * invd;
    }
}

__global__ __launch_bounds__(256) void k_wsum(const int* __restrict__ off, const float* __restrict__ w,
                       float* __restrict__ ws, int n) {
    for (int i = blockIdx.x * blockDim.x + threadIdx.x; i < n; i += gridDim.x * blockDim.x) {
        int s = off[i], e = off[i + 1]; float t = 0.f;
        for (int j = s; j < e; j++) t += w[j];
        ws[i] = t;
    }
}

// ---------------- BN column stats (bf16 input) ----------------
__global__ __launch_bounds__(256) void k_stats64b(const u16* __restrict__ x, int n, float* __restrict__ acc) {
    int c = threadIdx.x & 63, r4 = threadIdx.x >> 6;
    float s = 0.f, q = 0.f;
    for (int i = blockIdx.x * 4 + r4; i < n; i += gridDim.x * 4) {
        float v = b2f(x[(size_t)i * 64 + c]); s += v; q = fmaf(v, v, q);
    }
    __shared__ float ls[512];
    ls[threadIdx.x] = s; ls[256 + threadIdx.x] = q;
    __syncthreads();
    if (r4 == 0) {
        atomicAdd(&acc[c], ls[c] + ls[c + 64] + ls[c + 128] + ls[c + 192]);
        atomicAdd(&acc[64 + c], ls[256 + c] + ls[256 + c + 64] + ls[256 + c + 128] + ls[256 + c + 192]);
    }
}

// f32 input, small D: 1 row/thread, wave shuffle-reduce, 2D atomics/block
template <int D>
__global__ __launch_bounds__(256) void k_stats_small(const float* __restrict__ x, int n, float* __restrict__ acc) {
    float s[D], q[D];
#pragma unroll
    for (int k = 0; k < D; k++) { s[k] = 0.f; q[k] = 0.f; }
    for (int i = blockIdx.x * blockDim.x + threadIdx.x; i < n; i += gridDim.x * blockDim.x) {
#pragma unroll
        for (int k = 0; k < D; k++) { float v = x[(size_t)i * D + k]; s[k] += v; q[k] = fmaf(v, v, q[k]); }
    }
#pragma unroll
    for (int k = 0; k < D; k++) {
#pragma unroll
        for (int o = 32; o > 0; o >>= 1) {
            s[k] += __shfl_down(s[k], o);
            q[k] += __shfl_down(q[k], o);
        }
    }
    __shared__ float ls[4][2 * D];
    int lane = threadIdx.x & 63, wv = threadIdx.x >> 6;
    if (lane == 0) {
#pragma unroll
        for (int k = 0; k < D; k++) { ls[wv][k] = s[k]; ls[wv][D + k] = q[k]; }
    }
    __syncthreads();
    int t = threadIdx.x;
    if (t < 2 * D) atomicAdd(&acc[t], ls[0][t] + ls[1][t] + ls[2][t] + ls[3][t]);
}

// ---------------- fold BN into weights (2 param sets in one launch; block 0=A, 1=B) ------
struct FoldArgs {
    const float *Wrel, *brel, *Wroot, *gs, *bs, *accs, *gd, *bd, *accd;
    float invNs, invNd;
    int DSv, DDv;
    float *Wr_o, *Wt_o, *b0_o, *bw_o;
    u16* Bfrag;
};

__global__ __launch_bounds__(256) void k_fold2(FoldArgs A, FoldArgs B) {
    const FoldArgs F = blockIdx.x ? B : A;
    __shared__ float sa[128], sbe[128];
    __shared__ float rb0[4][64], rbw[4][64];
    int t = threadIdx.x;
    int total = F.DSv + F.DDv;
    for (int k = t; k < total; k += 256) {
        bool isrc = k < F.DSv;
        int kk = isrc ? k : k - F.DSv;
        const float* acc = isrc ? F.accs : F.accd;
        float invN = isrc ? F.invNs : F.invNd;
        int D = isrc ? F.DSv : F.DDv;
        float g = isrc ? F.gs[kk] : F.gd[kk];
        float b = isrc ? F.bs[kk] : F.bd[kk];
        float m = acc[kk] * invN;
        float var = acc[D + kk] * invN - m * m;
        float a = g * rsqrtf(var + EPSf);
        sa[k] = a; sbe[k] = b - m * a;
    }
    __syncthreads();
    int h = t & 63, q = t >> 6;
    float bw = 0.f, b0 = 0.f;
    for (int k = q; k < F.DSv; k += 4) {
        float wv = F.Wrel[k * 64 + h];
        float wf = sa[k] * wv;
        F.Wr_o[k * 64 + h] = wf;
        bw = fmaf(sbe[k], wv, bw);
        if (F.Bfrag) frag_store(F.Bfrag, k, h, wf);
    }
    for (int k = q; k < F.DDv; k += 4) {
        float wv = F.Wroot[k * 64 + h];
        float wf = sa[F.DSv + k] * wv;
        F.Wt_o[k * 64 + h] = wf;
        b0 = fmaf(sbe[F.DSv + k], wv, b0);
        if (F.Bfrag) frag_store(F.Bfrag, 64 + k, h, wf);
    }
    rb0[q][h] = b0; rbw[q][h] = bw;
    __syncthreads();
    if (q == 0) {
        F.b0_o[h] = F.brel[h] + rb0[0][h] + rb0[1][h] + rb0[2][h] + rb0[3][h];
        F.bw_o[h] = rbw[0][h] + rbw[1][h] + rbw[2][h] + rbw[3][h];
    }
}

// ---------------- layer-0 helpers ----------------
template <int DS>
__global__ __launch_bounds__(256) void k_agg(const float* __restrict__ xs, const int* __restrict__ off,
                      const int* __restrict__ col, const float* __restrict__ w,
                      float* __restrict__ agg, int n) {
    int lane = threadIdx.x & 63;
    int wid = (blockIdx.x * blockDim.x + threadIdx.x) >> 6;
    int nw = (gridDim.x * blockDim.x) >> 6;
    for (int i = wid; i < n; i += nw) {
        int s = off[i], e = off[i + 1];
        if (lane < DS) {
            float a0 = 0.f, a1 = 0.f, a2 = 0.f, a3 = 0.f;
            int j = s;
            for (; j + 3 < e; j += 4) {
                int c0 = col[j], c1 = col[j + 1], c2 = col[j + 2], c3 = col[j + 3];
                float w0 = w[j], w1 = w[j + 1], w2 = w[j + 2], w3 = w[j + 3];
                a0 = fmaf(w0, xs[(size_t)c0 * DS + lane], a0);
                a1 = fmaf(w1, xs[(size_t)c1 * DS + lane], a1);
                a2 = fmaf(w2, xs[(size_t)c2 * DS + lane], a2);
                a3 = fmaf(w3, xs[(size_t)c3 * DS + lane], a3);
            }
            for (; j < e; j++) a0 = fmaf(w[j], xs[(size_t)col[j] * DS + lane], a0);
            agg[(size_t)i * DS + lane] = (a0 + a1) + (a2 + a3);
        }
    }
}

__global__ __launch_bounds__(256) void k_agg1(const float* __restrict__ xs, const int* __restrict__ off,
                       const int* __restrict__ col, const float* __restrict__ w,
                       float* __restrict__ agg, int n) {
    for (int i = blockIdx.x * blockDim.x + threadIdx.x; i < n; i += gridDim.x * blockDim.x) {
        int s = off[i], e = off[i + 1]; float a = 0.f;
        for (int j = s; j < e; j++) a = fmaf(w[j], xs[col[j]], a);
        agg[i] = a;
    }
}

// layer-0 small-K GEMM: thread per (node, h); bf16 output
template <int KS, int KD>
__global__ __launch_bounds__(256) void k_gemm0(const float* __restrict__ aggs, const float* __restrict__ xd,
                        const float* __restrict__ wsum,
                        const float* __restrict__ Wr, const float* __restrict__ Wt,
                        const float* __restrict__ b0, const float* __restrict__ bw,
                        u16* __restrict__ out, int n) {
    int idx = blockIdx.x * blockDim.x + threadIdx.x;
    int i = idx >> 6, h = idx & 63;
    if (i >= n) return;
    float acc = b0[h] + wsum[i] * bw[h];
#pragma unroll
    for (int k = 0; k < KS; k++) acc = fmaf(aggs[i * KS + k], Wr[k * 64 + h], acc);
#pragma unroll
    for (int k = 0; k < KD; k++) acc = fmaf(xd[i * KD + k], Wt[k * 64 + h], acc);
    out[(size_t)i * 64 + h] = f2b(fmaxf(acc, 0.0f));
}

// ---------------- FUSED layer: agg (gather) + MFMA GEMM + epilogue + next-layer BN stats ----
// Round-11 gather re-layout: round-11 profile showed k_layer latency-bound
// (VALUBusy 22%, hbm 9.5%, MfmaUtil 1%): 1M dependent 2B-per-lane gathers, 4 edges
// in flight. Now: wave = 4 edge-slots x 16 lanes; lane loads ushort4 (8B) of its
// edge's row -> 512 B / VMEM instr (4 edges at once), x2 unroll = 8 edges in flight;
// per-row cross-slot reduce via shfl_xor(16,32); row offsets prefetched via shfl.
__global__ __launch_bounds__(256, 2) void k_layer(
        const u16* __restrict__ xs, const u16* __restrict__ xr,
        const int* __restrict__ off, const int* __restrict__ col, const float* __restrict__ w,
        const float* __restrict__ wsum, const u16* __restrict__ Bfrag,
        const float* __restrict__ b0v, const float* __restrict__ bwv,
        u16* __restrict__ out, float* __restrict__ statacc, int n) {
    __shared__ __align__(16) u16 lagg[4][16][72];
    __shared__ float lstat[4][2][64];
    int t = threadIdx.x;
    int wv = t >> 6, l = t & 63;
    int lrow = l & 15, lkg = l >> 4;
    int base = blockIdx.x * 64 + wv * 16;
    // phase 1: aggregate (4 edges per instruction, 8 in flight)
    {
        int g = l >> 4, qi = l & 15;
        int offv = 0;
        if (l < 17) { int idx = base + l; offv = off[idx > n ? n : idx]; }
        for (int r = 0; r < 16; ++r) {
            int s = __shfl(offv, r);
            int e = __shfl(offv, r + 1);
            float a0 = 0.f, a1 = 0.f, a2 = 0.f, a3 = 0.f;
            for (int j = s; j < e; j += 8) {
                int remA = e - j;
                int iA = j + (g < remA ? g : 0);
                float wA = w[iA]; if (g >= remA) wA = 0.f;
                int cA = col[iA];
                ushort4 fA = *(const ushort4*)(xs + (size_t)cA * 64 + qi * 4);
                a0 = fmaf(wA, b2f(fA.x), a0);
                a1 = fmaf(wA, b2f(fA.y), a1);
                a2 = fmaf(wA, b2f(fA.z), a2);
                a3 = fmaf(wA, b2f(fA.w), a3);
                int remB = remA - 4;
                if (remB > 0) {
                    int iB = j + 4 + (g < remB ? g : 0);
                    float wB = w[iB]; if (g >= remB) wB = 0.f;
                    int cB = col[iB];
                    ushort4 fB = *(const ushort4*)(xs + (size_t)cB * 64 + qi * 4);
                    a0 = fmaf(wB, b2f(fB.x), a0);
                    a1 = fmaf(wB, b2f(fB.y), a1);
                    a2 = fmaf(wB, b2f(fB.z), a2);
                    a3 = fmaf(wB, b2f(fB.w), a3);
                }
            }
            a0 += __shfl_xor(a0, 16); a0 += __shfl_xor(a0, 32);
            a1 += __shfl_xor(a1, 16); a1 += __shfl_xor(a1, 32);
            a2 += __shfl_xor(a2, 16); a2 += __shfl_xor(a2, 32);
            a3 += __shfl_xor(a3, 16); a3 += __shfl_xor(a3, 32);
            if (g == 0) {
                ushort4 o;
                o.x = f2b(a0); o.y = f2b(a1); o.z = f2b(a2); o.w = f2b(a3);
                *(ushort4*)&lagg[wv][r][qi * 4] = o;
            }
        }
    }
    // phase 2: MFMA (per-wave LDS region: wave-synchronous, no barrier needed)
    const u16* Bl = Bfrag + l * 8;
    f4v acc0 = {0.f, 0.f, 0.f, 0.f};
    f4v acc1 = acc0, acc2 = acc0, acc3 = acc0;
#define LSTEP(ks, APTR)                                                       \
    {                                                                         \
        s8v a = *(const s8v*)(APTR);                                          \
        s8v f0 = *(const s8v*)(Bl + ((ks) * 4 + 0) * 512);                    \
        s8v f1 = *(const s8v*)(Bl + ((ks) * 4 + 1) * 512);                    \
        s8v f2 = *(const s8v*)(Bl + ((ks) * 4 + 2) * 512);                    \
        s8v f3 = *(const s8v*)(Bl + ((ks) * 4 + 3) * 512);                    \
        acc0 = __builtin_amdgcn_mfma_f32_16x16x32_bf16(a, f0, acc0, 0, 0, 0); \
        acc1 = __builtin_amdgcn_mfma_f32_16x16x32_bf16(a, f1, acc1, 0, 0, 0); \
        acc2 = __builtin_amdgcn_mfma_f32_16x16x32_bf16(a, f2, acc2, 0, 0, 0); \
        acc3 = __builtin_amdgcn_mfma_f32_16x16x32_bf16(a, f3, acc3, 0, 0, 0); \
    }
    LSTEP(0, &lagg[wv][lrow][lkg * 8])
    LSTEP(1, &lagg[wv][lrow][32 + lkg * 8])
    int arow = base + lrow; if (arow >= n) arow = 0;
    const u16* xp = xr + (size_t)arow * 64 + lkg * 8;
    LSTEP(2, xp)
    LSTEP(3, xp + 32)
#undef LSTEP
    // phase 3: epilogue + stats
    int orow = base + lkg * 4;
    bool ok0 = orow + 0 < n, ok1 = orow + 1 < n, ok2 = orow + 2 < n, ok3 = orow + 3 < n;
    float ws0 = ok0 ? wsum[orow + 0] : 0.f;
    float ws1 = ok1 ? wsum[orow + 1] : 0.f;
    float ws2 = ok2 ? wsum[orow + 2] : 0.f;
    float ws3 = ok3 ? wsum[orow + 3] : 0.f;
#define EPI(ACC, ct)                                                          \
    {                                                                         \
        int c = (ct) * 16 + lrow;                                             \
        float bb = b0v[c], wb = bwv[c];                                       \
        float v0 = ok0 ? fmaxf(ACC[0] + bb + ws0 * wb, 0.f) : 0.f;            \
        float v1 = ok1 ? fmaxf(ACC[1] + bb + ws1 * wb, 0.f) : 0.f;            \
        float v2 = ok2 ? fmaxf(ACC[2] + bb + ws2 * wb, 0.f) : 0.f;            \
        float v3 = ok3 ? fmaxf(ACC[3] + bb + ws3 * wb, 0.f) : 0.f;            \
        if (ok0) out[(size_t)(orow + 0) * 64 + c] = f2b(v0);                  \
        if (ok1) out[(size_t)(orow + 1) * 64 + c] = f2b(v1);                  \
        if (ok2) out[(size_t)(orow + 2) * 64 + c] = f2b(v2);                  \
        if (ok3) out[(size_t)(orow + 3) * 64 + c] = f2b(v3);                  \
        if (statacc) {                                                        \
            float sv = (v0 + v1) + (v2 + v3);                                 \
            float qv = fmaf(v0, v0, fmaf(v1, v1, fmaf(v2, v2, v3 * v3)));     \
            sv += __shfl_xor(sv, 16); sv += __shfl_xor(sv, 32);               \
            qv += __shfl_xor(qv, 16); qv += __shfl_xor(qv, 32);               \
            if (lkg == 0) { lstat[wv][0][c] = sv; lstat[wv][1][c] = qv; }     \
        }                                                                     \
    }
    EPI(acc0, 0)
    EPI(acc1, 1)
    EPI(acc2, 2)
    EPI(acc3, 3)
#undef EPI
    if (statacc) {
        __syncthreads();
        if (t < 128) {
            int c = t & 63, p = t >> 6;
            atomicAdd(&statacc[p * 64 + c],
                      lstat[0][p][c] + lstat[1][p][c] + lstat[2][p][c] + lstat[3][p][c]);
        }
    }
}

// ---------------- pooling ----------------
__global__ __launch_bounds__(256) void k_seg_count(const int* __restrict__ batch, int n, int* __restrict__ cnt) {
    int i = blockIdx.x * blockDim.x + threadIdx.x;
    if (i >= n) return;
    int lane = threadIdx.x & 63;
    int b = batch[i];
    int bprev = __shfl_up(b, 1);
    bool head = (lane == 0) || (b != bprev);
    unsigned long long hb = __ballot(head);
    if (head) {
        unsigned long long mask = (lane == 63) ? 0ULL : (hb >> (lane + 1));
        int wstart = i - lane;
        int nvalid = min(64, n - wstart);
        int end = (mask == 0ULL) ? nvalid : (lane + 1 + __ffsll((long long)mask) - 1);
        atomicAdd(&cnt[b], end - lane);
    }
}

// bf16 features; 128 rows/block (32/walker); batch sorted -> ~1 run/walker
__global__ __launch_bounds__(256) void k_pool_accum(const u16* __restrict__ x, const int* __restrict__ batch,
                             int n, float* __restrict__ sums) {
    int c = threadIdx.x & 63, r4 = threadIdx.x >> 6;
    int base = blockIdx.x * 128 + r4 * 32;
    int end = min(n, base + 32);
    float acc = 0.f; int cur = -1;
    for (int i = base; i < end; ++i) {
        int b = batch[i];
        if (b != cur) {
            if (cur >= 0) atomicAdd(&sums[cur * 64 + c], acc);
            acc = 0.f; cur = b;
        }
        acc += b2f(x[(size_t)i * 64 + c]);
    }
    if (cur >= 0) atomicAdd(&sums[cur * 64 + c], acc);
}

__global__ __launch_bounds__(256) void k_pool_div(const float* __restrict__ sv, const float* __restrict__ sc,
                           const int* __restrict__ cv, const int* __restrict__ cc2,
                           float* __restrict__ out) {
    int idx = blockIdx.x * blockDim.x + threadIdx.x;
    if (idx >= NBb * 128) return;
    int b = idx >> 7, j = idx & 127;
    float v;
    if (j < 64) v = sv[b * 64 + j] / fmaxf((float)cv[b], 1.0f);
    else        v = sc[b * 64 + (j - 64)] / fmaxf((float)cc2[b], 1.0f);
    out[idx] = v;
}

// ==================================================================
extern "C" void kernel_launch(void* const* d_in, const int* in_sizes, int n_in,
                              void* d_out, int out_size, void* d_ws, size_t ws_size,
                              hipStream_t stream) {
    (void)in_sizes; (void)n_in; (void)out_size; (void)ws_size;
    const float* var_feats = (const float*)d_in[0];
    const float* cstr_feats = (const float*)d_in[1];
    const float* edge_attr = (const float*)d_in[2];
    const float* Wrel_v0 = (const float*)d_in[3];
    const float* brel_v0 = (const float*)d_in[4];
    const float* Wroot_v0 = (const float*)d_in[5];
    const float* Wrel_c0 = (const float*)d_in[6];
    const float* brel_c0 = (const float*)d_in[7];
    const float* Wroot_c0 = (const float*)d_in[8];
    const float* g_v0 = (const float*)d_in[9];
    const float* b_v0 = (const float*)d_in[10];
    const float* g_c0 = (const float*)d_in[11];
    const float* b_c0 = (const float*)d_in[12];
    const float* Wrel_v = (const float*)d_in[13];
    const float* brel_v = (const float*)d_in[14];
    const float* Wroot_v = (const float*)d_in[15];
    const float* Wrel_c = (const float*)d_in[16];
    const float* brel_c = (const float*)d_in[17];
    const float* Wroot_c = (const float*)d_in[18];
    const float* g_v = (const float*)d_in[19];
    const float* b_v = (const float*)d_in[20];
    const float* g_c = (const float*)d_in[21];
    const float* b_c = (const float*)d_in[22];
    const int* edge_index = (const int*)d_in[23];
    const int* var_batch = (const int*)d_in[24];
    const int* cstr_batch = (const int*)d_in[25];
    const int* src_c = edge_index;
    const int* dst_v = edge_index + NEn;
    float* out = (float*)d_out;

    // ---- workspace carve-out ----
    char* ws = (char*)d_ws;
    size_t off_b = 0;
    auto alloc = [&](size_t bytes) -> char* {
        char* p = ws + off_b;
        off_b = (off_b + bytes + 255) & ~(size_t)255;
        return p;
    };
    // bf16 feature ping-pong buffers
    u16* Vb[2] = { (u16*)alloc((size_t)NVn * 64 * 2), (u16*)alloc((size_t)NVn * 64 * 2) };
    u16* Cb[2] = { (u16*)alloc((size_t)NCn * 64 * 2), (u16*)alloc((size_t)NCn * 64 * 2) };
    // layer-0 f32 agg scratch (small D)
    float* aggV0 = (float*)alloc((size_t)NVn * 4);        // [NV,1]
    float* aggC0 = (float*)alloc((size_t)NCn * 9 * 4);    // [NC,9]
    int* off_v = (int*)alloc((size_t)(NVn + 1) * 4);
    int* cur_v = (int*)alloc((size_t)NVn * 4);
    int* col_v = (int*)alloc((size_t)NEn * 4);
    float* w_v = (float*)alloc((size_t)NEn * 4);
    int* off_c = (int*)alloc((size_t)(NCn + 1) * 4);
    int* cur_c = (int*)alloc((size_t)NCn * 4);
    int* col_c = (int*)alloc((size_t)NEn * 4);
    float* w_c = (float*)alloc((size_t)NEn * 4);
    float* wsum_v = (float*)alloc((size_t)NVn * 4);
    float* wsum_c = (float*)alloc((size_t)NCn * 4);
    int* degzone = (int*)alloc((size_t)(NVn + NCn) * 4);
    int* degv = degzone;
    int* degc = degzone + NVn;
    int* bsum = (int*)alloc(1024 * 4);
    // zero-init zone (one memset): stats accums + pool sums + counts
    float* zzone = (float*)alloc(4992 * 4);
    float* accL0v = zzone;            // 32 (18 used)
    float* accL0c = zzone + 32;       // 8 (2 used)
    float* accLv[3], *accLc[3];
    for (int l = 0; l < 3; l++) { accLv[l] = zzone + 64 + l * 256; accLc[l] = zzone + 64 + l * 256 + 128; }
    float* pool_sv = zzone + 832;     // 2048
    float* pool_sc = zzone + 2880;    // 2048
    int* cnt_v = (int*)(zzone + 4928);  // 32
    int* cnt_c = (int*)(zzone + 4960);  // 32
    // folded weights
    float* Wr_v = (float*)alloc(4096 * 4);
    float* Wt_v = (float*)alloc(4096 * 4);
    float* b0_v = (float*)alloc(64 * 4);
    float* bw_v = (float*)alloc(64 * 4);
    float* Wr_c = (float*)alloc(4096 * 4);
    float* Wt_c = (float*)alloc(4096 * 4);
    float* b0_c = (float*)alloc(64 * 4);
    float* bw_c = (float*)alloc(64 * 4);
    // bf16 MFMA B-fragment buffers: [ks4][ct4][lane64][8 bf16]
    u16* Bf_v = (u16*)alloc(8192 * 2);
    u16* Bf_c = (u16*)alloc(8192 * 2);

    const float invNV = 1.0f / (float)NVn;
    const float invNC = 1.0f / (float)NCn;

    // ---- init ----
    hipMemsetAsync(degzone, 0, (size_t)(NVn + NCn) * 4, stream);
    hipMemsetAsync(zzone, 0, 4992 * 4, stream);

    // ---- build CSR both directions ----
    k_count_deg<<<2048, 256, 0, stream>>>(src_c, dst_v, degv, degc);
    int nbv = (NVn + 1023) / 1024;  // 196
    int nbc = (NCn + 1023) / 1024;  // 98
    k_scan_block<<<nbv, 256, 0, stream>>>(degv, NVn, bsum);
    k_scan_tops<<<1, 1024, 0, stream>>>(bsum, nbv);
    k_scan_final<<<nbv, 256, 0, stream>>>(degv, NVn, bsum, off_v, cur_v);
    k_scan_block<<<nbc, 256, 0, stream>>>(degc, NCn, bsum);
    k_scan_tops<<<1, 1024, 0, stream>>>(bsum, nbc);
    k_scan_final<<<nbc, 256, 0, stream>>>(degc, NCn, bsum, off_c, cur_c);
    k_fill<<<2048, 256, 0, stream>>>(dst_v, src_c, edge_attr, off_v, cur_v, col_v, w_v);
    k_fill<<<2048, 256, 0, stream>>>(src_c, dst_v, edge_attr, off_c, cur_c, col_c, w_c);
    k_wsum<<<784, 256, 0, stream>>>(off_v, w_v, wsum_v, NVn);
    k_wsum<<<392, 256, 0, stream>>>(off_c, w_c, wsum_c, NCn);

    // ---- layer 0 (var: 9 feats, cstr: 1 feat) ----
    k_stats_small<9><<<784, 256, 0, stream>>>(var_feats, NVn, accL0v);
    k_stats_small<1><<<392, 256, 0, stream>>>(cstr_feats, NCn, accL0c);
    {
        FoldArgs fv = { Wrel_v0, brel_v0, Wroot_v0, g_c0, b_c0, accL0c, g_v0, b_v0, accL0v,
                        invNC, invNV, 1, 9, Wr_v, Wt_v, b0_v, bw_v, (u16*)nullptr };
        FoldArgs fc = { Wrel_c0, brel_c0, Wroot_c0, g_v0, b_v0, accL0v, g_c0, b_c0, accL0c,
                        invNV, invNC, 9, 1, Wr_c, Wt_c, b0_c, bw_c, (u16*)nullptr };
        k_fold2<<<2, 256, 0, stream>>>(fv, fc);
    }
    k_agg1<<<784, 256, 0, stream>>>(cstr_feats, off_v, col_v, w_v, aggV0, NVn);       // [NV,1]
    k_agg<9><<<2048, 256, 0, stream>>>(var_feats, off_c, col_c, w_c, aggC0, NCn);     // [NC,9]
    k_gemm0<1, 9><<<(NVn * 64 + 255) / 256, 256, 0, stream>>>(aggV0, var_feats, wsum_v,
                                                              Wr_v, Wt_v, b0_v, bw_v, Vb[0], NVn);
    k_gemm0<9, 1><<<(NCn * 64 + 255) / 256, 256, 0, stream>>>(aggC0, cstr_feats, wsum_c,
                                                              Wr_c, Wt_c, b0_c, bw_c, Cb[0], NCn);
    k_stats64b<<<2048, 256, 0, stream>>>(Vb[0], NVn, accLv[0]);
    k_stats64b<<<2048, 256, 0, stream>>>(Cb[0], NCn, accLc[0]);

    // ---- layers 1..3 (fused agg+GEMM+stats) ----
    int cur = 0;
    for (int l = 0; l < 3; l++) {
        const float* Wrv = Wrel_v + (size_t)l * 4096;
        const float* brv = brel_v + (size_t)l * 64;
        const float* Wtv = Wroot_v + (size_t)l * 4096;
        const float* Wrc = Wrel_c + (size_t)l * 4096;
        const float* brc = brel_c + (size_t)l * 64;
        const float* Wtc = Wroot_c + (size_t)l * 4096;
        const float* gvl = g_v + (size_t)l * 64; const float* bvl = b_v + (size_t)l * 64;
        const float* gcl = g_c + (size_t)l * 64; const float* bcl = b_c + (size_t)l * 64;

        FoldArgs fv = { Wrv, brv, Wtv, gcl, bcl, accLc[l], gvl, bvl, accLv[l],
                        invNC, invNV, 64, 64, Wr_v, Wt_v, b0_v, bw_v, Bf_v };
        FoldArgs fc = { Wrc, brc, Wtc, gvl, bvl, accLv[l], gcl, bcl, accLc[l],
                        invNV, invNC, 64, 64, Wr_c, Wt_c, b0_c, bw_c, Bf_c };
        k_fold2<<<2, 256, 0, stream>>>(fv, fc);

        int nxt = cur ^ 1;
        float* sv = (l < 2) ? accLv[l + 1] : (float*)nullptr;
        float* sc = (l < 2) ? accLc[l + 1] : (float*)nullptr;
        k_layer<<<(NVn + 63) / 64, 256, 0, stream>>>(Cb[cur], Vb[cur], off_v, col_v, w_v,
                                                     wsum_v, Bf_v, b0_v, bw_v, Vb[nxt], sv, NVn);
        k_layer<<<(NCn + 63) / 64, 256, 0, stream>>>(Vb[cur], Cb[cur], off_c, col_c, w_c,
                                                     wsum_c, Bf_c, b0_c, bw_c, Cb[nxt], sc, NCn);
        cur = nxt;
    }

    // ---- pooling ----
    k_seg_count<<<(NVn + 255) / 256, 256, 0, stream>>>(var_batch, NVn, cnt_v);
    k_seg_count<<<(NCn + 255) / 256, 256, 0, stream>>>(cstr_batch, NCn, cnt_c);
    k_pool_accum<<<(NVn + 127) / 128, 256, 0, stream>>>(Vb[cur], var_batch, NVn, pool_sv);
    k_pool_accum<<<(NCn + 127) / 128, 256, 0, stream>>>(Cb[cur], cstr_batch, NCn, pool_sc);
    k_pool_div<<<(NBb * 128 + 255) / 256, 256, 0, stream>>>(pool_sv, pool_sc, cnt_v, cnt_c, out);
}

// Round 13
// 983.165 us; speedup vs baseline: 1.3390x; 1.0814x over previous
//
#include <hip/hip_runtime.h>

// Problem constants (match reference setup_inputs)
constexpr int NVn = 200000;   // var nodes, 9 feats in
constexpr int NCn = 100000;   // cstr nodes, 1 feat in
constexpr int NEn = 1000000;  // edges
constexpr int NBb = 32;       // graphs
#define EPSf 1e-5f

typedef unsigned short u16;
typedef __attribute__((ext_vector_type(8))) short s8v;   // 8 bf16 (4 VGPRs)
typedef __attribute__((ext_vector_type(4))) float f4v;   // 4 f32 acc

// f32 -> bf16 bits, round-to-nearest-even
static __device__ __forceinline__ u16 f2b(float f) {
    union { float f; unsigned u; } x; x.f = f;
    return (u16)((x.u + 0x7FFFu + ((x.u >> 16) & 1u)) >> 16);
}
static __device__ __forceinline__ float b2f(u16 u) {
    union { unsigned u; float f; } x; x.u = ((unsigned)u) << 16; return x.f;
}

// store folded weight W[kg][h] (kg in 0..127, h in 0..63) into MFMA B-fragment order:
// fragment (ks=kg>>5, ct=h>>4), lane = ((kg>>3)&3)<<4 | (h&15), elem j = kg&7
static __device__ __forceinline__ void frag_store(u16* B, int kg, int h, float w) {
    int ks = kg >> 5, g = (kg >> 3) & 3, j = kg & 7, ct = h >> 4;
    int lane = (g << 4) | (h & 15);
    B[((((ks << 2) | ct) << 6) | lane) * 8 + j] = f2b(w);
}

// ---------------- degree count ----------------
__global__ __launch_bounds__(256) void k_count_deg(const int* __restrict__ src, const int* __restrict__ dst,
                            int* __restrict__ degv, int* __restrict__ degc) {
    for (int e = blockIdx.x * blockDim.x + threadIdx.x; e < NEn; e += gridDim.x * blockDim.x) {
        atomicAdd(&degv[dst[e]], 1);
        atomicAdd(&degc[src[e]], 1);
    }
}

// ---------------- exclusive scan (3 kernels, 1024 elems/block) ----------------
__global__ __launch_bounds__(256) void k_scan_block(const int* __restrict__ deg, int n, int* __restrict__ bsum) {
    __shared__ int s[256];
    int base = blockIdx.x * 1024;
    int t = threadIdx.x;
    int v = 0;
#pragma unroll
    for (int j = 0; j < 4; j++) { int idx = base + t * 4 + j; if (idx < n) v += deg[idx]; }
    s[t] = v; __syncthreads();
    for (int o = 128; o > 0; o >>= 1) { if (t < o) s[t] += s[t + o]; __syncthreads(); }
    if (t == 0) bsum[blockIdx.x] = s[0];
}

__global__ __launch_bounds__(1024) void k_scan_tops(int* bsum, int nb) {
    __shared__ int s[1024];
    int t = threadIdx.x;
    int v = (t < nb) ? bsum[t] : 0;
    s[t] = v; __syncthreads();
    for (int o = 1; o < 1024; o <<= 1) {
        int x = (t >= o) ? s[t - o] : 0; __syncthreads();
        s[t] += x; __syncthreads();
    }
    if (t < nb) bsum[t] = s[t] - v;  // exclusive
}

__global__ __launch_bounds__(256) void k_scan_final(const int* __restrict__ deg, int n, const int* __restrict__ bsum,
                             int* __restrict__ off, int* __restrict__ cur) {
    __shared__ int s[256];
    int base = blockIdx.x * 1024, t = threadIdx.x;
    int d[4], loc[4], sum = 0;
#pragma unroll
    for (int j = 0; j < 4; j++) {
        int idx = base + t * 4 + j;
        d[j] = (idx < n) ? deg[idx] : 0;
        loc[j] = sum; sum += d[j];
    }
    s[t] = sum; __syncthreads();
    int v = sum;
    for (int o = 1; o < 256; o <<= 1) {
        int x = (t >= o) ? s[t - o] : 0; __syncthreads();
        s[t] += x; __syncthreads();
    }
    int texcl = s[t] - v + bsum[blockIdx.x];
#pragma unroll
    for (int j = 0; j < 4; j++) {
        int idx = base + t * 4 + j;
        if (idx < n) {
            int o2 = texcl + loc[j];
            off[idx] = o2; cur[idx] = o2;
            if (idx == n - 1) off[n] = o2 + d[j];
        }
    }
}

// ---------------- CSR fill (w = ew / deg) ----------------
__global__ __launch_bounds__(256) void k_fill(const int* __restrict__ key, const int* __restrict__ other,
                       const float* __restrict__ ew, const int* __restrict__ off,
                       int* __restrict__ cur, int* __restrict__ col, float* __restrict__ w) {
    for (int e = blockIdx.x * blockDim.x + threadIdx.x; e < NEn; e += gridDim.x * blockDim.x) {
        int d = key[e];
        int p = atomicAdd(&cur[d], 1);
        col[p] = other[e];
        float invd = 1.0f / (float)(off[d + 1] - off[d]);
        w[p] = ew[e] * invd;
    }
}

__global__ __launch_bounds__(256) void k_wsum(const int* __restrict__ off, const float* __restrict__ w,
                       float* __restrict__ ws, int n) {
    for (int i = blockIdx.x * blockDim.x + threadIdx.x; i < n; i += gridDim.x * blockDim.x) {
        int s = off[i], e = off[i + 1]; float t = 0.f;
        for (int j = s; j < e; j++) t += w[j];
        ws[i] = t;
    }
}

// ---------------- BN column stats (bf16 input) ----------------
__global__ __launch_bounds__(256) void k_stats64b(const u16* __restrict__ x, int n, float* __restrict__ acc) {
    int c = threadIdx.x & 63, r4 = threadIdx.x >> 6;
    float s = 0.f, q = 0.f;
    for (int i = blockIdx.x * 4 + r4; i < n; i += gridDim.x * 4) {
        float v = b2f(x[(size_t)i * 64 + c]); s += v; q = fmaf(v, v, q);
    }
    __shared__ float ls[512];
    ls[threadIdx.x] = s; ls[256 + threadIdx.x] = q;
    __syncthreads();
    if (r4 == 0) {
        atomicAdd(&acc[c], ls[c] + ls[c + 64] + ls[c + 128] + ls[c + 192]);
        atomicAdd(&acc[64 + c], ls[256 + c] + ls[256 + c + 64] + ls[256 + c + 128] + ls[256 + c + 192]);
    }
}

// f32 input, small D: 1 row/thread, wave shuffle-reduce, 2D atomics/block
template <int D>
__global__ __launch_bounds__(256) void k_stats_small(const float* __restrict__ x, int n, float* __restrict__ acc) {
    float s[D], q[D];
#pragma unroll
    for (int k = 0; k < D; k++) { s[k] = 0.f; q[k] = 0.f; }
    for (int i = blockIdx.x * blockDim.x + threadIdx.x; i < n; i += gridDim.x * blockDim.x) {
#pragma unroll
        for (int k = 0; k < D; k++) { float v = x[(size_t)i * D + k]; s[k] += v; q[k] = fmaf(v, v, q[k]); }
    }
#pragma unroll
    for (int k = 0; k < D; k++) {
#pragma unroll
        for (int o = 32; o > 0; o >>= 1) {
            s[k] += __shfl_down(s[k], o);
            q[k] += __shfl_down(q[k], o);
        }
    }
    __shared__ float ls[4][2 * D];
    int lane = threadIdx.x & 63, wv = threadIdx.x >> 6;
    if (lane == 0) {
#pragma unroll
        for (int k = 0; k < D; k++) { ls[wv][k] = s[k]; ls[wv][D + k] = q[k]; }
    }
    __syncthreads();
    int t = threadIdx.x;
    if (t < 2 * D) atomicAdd(&acc[t], ls[0][t] + ls[1][t] + ls[2][t] + ls[3][t]);
}

// ---------------- fold BN into weights (2 param sets in one launch; block 0=A, 1=B) ------
struct FoldArgs {
    const float *Wrel, *brel, *Wroot, *gs, *bs, *accs, *gd, *bd, *accd;
    float invNs, invNd;
    int DSv, DDv;
    float *Wr_o, *Wt_o, *b0_o, *bw_o;
    u16* Bfrag;
};

__global__ __launch_bounds__(256) void k_fold2(FoldArgs A, FoldArgs B) {
    const FoldArgs F = blockIdx.x ? B : A;
    __shared__ float sa[128], sbe[128];
    __shared__ float rb0[4][64], rbw[4][64];
    int t = threadIdx.x;
    int total = F.DSv + F.DDv;
    for (int k = t; k < total; k += 256) {
        bool isrc = k < F.DSv;
        int kk = isrc ? k : k - F.DSv;
        const float* acc = isrc ? F.accs : F.accd;
        float invN = isrc ? F.invNs : F.invNd;
        int D = isrc ? F.DSv : F.DDv;
        float g = isrc ? F.gs[kk] : F.gd[kk];
        float b = isrc ? F.bs[kk] : F.bd[kk];
        float m = acc[kk] * invN;
        float var = acc[D + kk] * invN - m * m;
        float a = g * rsqrtf(var + EPSf);
        sa[k] = a; sbe[k] = b - m * a;
    }
    __syncthreads();
    int h = t & 63, q = t >> 6;
    float bw = 0.f, b0 = 0.f;
    for (int k = q; k < F.DSv; k += 4) {
        float wv = F.Wrel[k * 64 + h];
        float wf = sa[k] * wv;
        F.Wr_o[k * 64 + h] = wf;
        bw = fmaf(sbe[k], wv, bw);
        if (F.Bfrag) frag_store(F.Bfrag, k, h, wf);
    }
    for (int k = q; k < F.DDv; k += 4) {
        float wv = F.Wroot[k * 64 + h];
        float wf = sa[F.DSv + k] * wv;
        F.Wt_o[k * 64 + h] = wf;
        b0 = fmaf(sbe[F.DSv + k], wv, b0);
        if (F.Bfrag) frag_store(F.Bfrag, 64 + k, h, wf);
    }
    rb0[q][h] = b0; rbw[q][h] = bw;
    __syncthreads();
    if (q == 0) {
        F.b0_o[h] = F.brel[h] + rb0[0][h] + rb0[1][h] + rb0[2][h] + rb0[3][h];
        F.bw_o[h] = rbw[0][h] + rbw[1][h] + rbw[2][h] + rbw[3][h];
    }
}

// ---------------- layer-0 helpers ----------------
template <int DS>
__global__ __launch_bounds__(256) void k_agg(const float* __restrict__ xs, const int* __restrict__ off,
                      const int* __restrict__ col, const float* __restrict__ w,
                      float* __restrict__ agg, int n) {
    int lane = threadIdx.x & 63;
    int wid = (blockIdx.x * blockDim.x + threadIdx.x) >> 6;
    int nw = (gridDim.x * blockDim.x) >> 6;
    for (int i = wid; i < n; i += nw) {
        int s = off[i], e = off[i + 1];
        if (lane < DS) {
            float a0 = 0.f, a1 = 0.f, a2 = 0.f, a3 = 0.f;
            int j = s;
            for (; j + 3 < e; j += 4) {
                int c0 = col[j], c1 = col[j + 1], c2 = col[j + 2], c3 = col[j + 3];
                float w0 = w[j], w1 = w[j + 1], w2 = w[j + 2], w3 = w[j + 3];
                a0 = fmaf(w0, xs[(size_t)c0 * DS + lane], a0);
                a1 = fmaf(w1, xs[(size_t)c1 * DS + lane], a1);
                a2 = fmaf(w2, xs[(size_t)c2 * DS + lane], a2);
                a3 = fmaf(w3, xs[(size_t)c3 * DS + lane], a3);
            }
            for (; j < e; j++) a0 = fmaf(w[j], xs[(size_t)col[j] * DS + lane], a0);
            agg[(size_t)i * DS + lane] = (a0 + a1) + (a2 + a3);
        }
    }
}

__global__ __launch_bounds__(256) void k_agg1(const float* __restrict__ xs, const int* __restrict__ off,
                       const int* __restrict__ col, const float* __restrict__ w,
                       float* __restrict__ agg, int n) {
    for (int i = blockIdx.x * blockDim.x + threadIdx.x; i < n; i += gridDim.x * blockDim.x) {
        int s = off[i], e = off[i + 1]; float a = 0.f;
        for (int j = s; j < e; j++) a = fmaf(w[j], xs[col[j]], a);
        agg[i] = a;
    }
}

// layer-0 small-K GEMM: thread per (node, h); bf16 output
template <int KS, int KD>
__global__ __launch_bounds__(256) void k_gemm0(const float* __restrict__ aggs, const float* __restrict__ xd,
                        const float* __restrict__ wsum,
                        const float* __restrict__ Wr, const float* __restrict__ Wt,
                        const float* __restrict__ b0, const float* __restrict__ bw,
                        u16* __restrict__ out, int n) {
    int idx = blockIdx.x * blockDim.x + threadIdx.x;
    int i = idx >> 6, h = idx & 63;
    if (i >= n) return;
    float acc = b0[h] + wsum[i] * bw[h];
#pragma unroll
    for (int k = 0; k < KS; k++) acc = fmaf(aggs[i * KS + k], Wr[k * 64 + h], acc);
#pragma unroll
    for (int k = 0; k < KD; k++) acc = fmaf(xd[i * KD + k], Wt[k * 64 + h], acc);
    out[(size_t)i * 64 + h] = f2b(fmaxf(acc, 0.0f));
}

// ---------------- FUSED layer: agg (gather) + MFMA GEMM + epilogue + next-layer BN stats ----
// Round-12 MLP fix: the serial per-row loop left only ~2 dependent gather chains in
// flight (VALUBusy 21%, hbm 10%, latency-bound). Now straight-line 8-edge fast path,
// batched by 8 rows: unrolled col/w loads (16), then unrolled ushort4 feature loads
// (16 independent, all in flight), then FMA + tail (deg>8 only) + shfl-reduce.
__global__ __launch_bounds__(256, 2) void k_layer(
        const u16* __restrict__ xs, const u16* __restrict__ xr,
        const int* __restrict__ off, const int* __restrict__ col, const float* __restrict__ w,
        const float* __restrict__ wsum, const u16* __restrict__ Bfrag,
        const float* __restrict__ b0v, const float* __restrict__ bwv,
        u16* __restrict__ out, float* __restrict__ statacc, int n) {
    __shared__ __align__(16) u16 lagg[4][16][72];
    __shared__ float lstat[4][2][64];
    int t = threadIdx.x;
    int wv = t >> 6, l = t & 63;
    int lrow = l & 15, lkg = l >> 4;
    int base = blockIdx.x * 64 + wv * 16;
    // phase 1: aggregate
    {
        int g = l >> 4, qi = l & 15;
        int offv = 0;
        if (l < 17) { int idx = base + l; offv = off[idx > n ? n : idx]; }
#pragma unroll
        for (int half = 0; half < 2; ++half) {
            int sA[8], eA[8], cA[8], cB[8];
            float wA[8], wB[8];
#pragma unroll
            for (int rr = 0; rr < 8; ++rr) {
                int r = half * 8 + rr;
                int s = __shfl(offv, r);
                int e = __shfl(offv, r + 1);
                sA[rr] = s; eA[rr] = e;
                int dA = e - s;
                int iA = (dA > 0) ? (s + (g < dA ? g : 0)) : 0;
                int dB = dA - 4;
                int iB = (dB > 0) ? (s + 4 + (g < dB ? g : 0)) : 0;
                cA[rr] = col[iA];
                cB[rr] = col[iB];
                float wa = w[iA]; if (g >= dA) wa = 0.f;
                float wb = w[iB]; if (g >= dB) wb = 0.f;
                wA[rr] = wa; wB[rr] = wb;
            }
            ushort4 fA[8], fB[8];
#pragma unroll
            for (int rr = 0; rr < 8; ++rr) {
                fA[rr] = *(const ushort4*)(xs + (size_t)cA[rr] * 64 + qi * 4);
                fB[rr] = *(const ushort4*)(xs + (size_t)cB[rr] * 64 + qi * 4);
            }
#pragma unroll
            for (int rr = 0; rr < 8; ++rr) {
                float a0 = fmaf(wA[rr], b2f(fA[rr].x), wB[rr] * b2f(fB[rr].x));
                float a1 = fmaf(wA[rr], b2f(fA[rr].y), wB[rr] * b2f(fB[rr].y));
                float a2 = fmaf(wA[rr], b2f(fA[rr].z), wB[rr] * b2f(fB[rr].z));
                float a3 = fmaf(wA[rr], b2f(fA[rr].w), wB[rr] * b2f(fB[rr].w));
                for (int j = sA[rr] + 8; j < eA[rr]; j += 4) {
                    int rem = eA[rr] - j;
                    int i2 = j + (g < rem ? g : 0);
                    float w2 = w[i2]; if (g >= rem) w2 = 0.f;
                    int c2 = col[i2];
                    ushort4 f2 = *(const ushort4*)(xs + (size_t)c2 * 64 + qi * 4);
                    a0 = fmaf(w2, b2f(f2.x), a0);
                    a1 = fmaf(w2, b2f(f2.y), a1);
                    a2 = fmaf(w2, b2f(f2.z), a2);
                    a3 = fmaf(w2, b2f(f2.w), a3);
                }
                a0 += __shfl_xor(a0, 16); a0 += __shfl_xor(a0, 32);
                a1 += __shfl_xor(a1, 16); a1 += __shfl_xor(a1, 32);
                a2 += __shfl_xor(a2, 16); a2 += __shfl_xor(a2, 32);
                a3 += __shfl_xor(a3, 16); a3 += __shfl_xor(a3, 32);
                if (g == 0) {
                    ushort4 o;
                    o.x = f2b(a0); o.y = f2b(a1); o.z = f2b(a2); o.w = f2b(a3);
                    *(ushort4*)&lagg[wv][half * 8 + rr][qi * 4] = o;
                }
            }
        }
    }
    // phase 2: MFMA (per-wave LDS region: wave-synchronous, no barrier needed)
    const u16* Bl = Bfrag + l * 8;
    f4v acc0 = {0.f, 0.f, 0.f, 0.f};
    f4v acc1 = acc0, acc2 = acc0, acc3 = acc0;
#define LSTEP(ks, APTR)                                                       \
    {                                                                         \
        s8v a = *(const s8v*)(APTR);                                          \
        s8v f0 = *(const s8v*)(Bl + ((ks) * 4 + 0) * 512);                    \
        s8v f1 = *(const s8v*)(Bl + ((ks) * 4 + 1) * 512);                    \
        s8v f2 = *(const s8v*)(Bl + ((ks) * 4 + 2) * 512);                    \
        s8v f3 = *(const s8v*)(Bl + ((ks) * 4 + 3) * 512);                    \
        acc0 = __builtin_amdgcn_mfma_f32_16x16x32_bf16(a, f0, acc0, 0, 0, 0); \
        acc1 = __builtin_amdgcn_mfma_f32_16x16x32_bf16(a, f1, acc1, 0, 0, 0); \
        acc2 = __builtin_amdgcn_mfma_f32_16x16x32_bf16(a, f2, acc2, 0, 0, 0); \
        acc3 = __builtin_amdgcn_mfma_f32_16x16x32_bf16(a, f3, acc3, 0, 0, 0); \
    }
    LSTEP(0, &lagg[wv][lrow][lkg * 8])
    LSTEP(1, &lagg[wv][lrow][32 + lkg * 8])
    int arow = base + lrow; if (arow >= n) arow = 0;
    const u16* xp = xr + (size_t)arow * 64 + lkg * 8;
    LSTEP(2, xp)
    LSTEP(3, xp + 32)
#undef LSTEP
    // phase 3: epilogue + stats
    int orow = base + lkg * 4;
    bool ok0 = orow + 0 < n, ok1 = orow + 1 < n, ok2 = orow + 2 < n, ok3 = orow + 3 < n;
    float ws0 = ok0 ? wsum[orow + 0] : 0.f;
    float ws1 = ok1 ? wsum[orow + 1] : 0.f;
    float ws2 = ok2 ? wsum[orow + 2] : 0.f;
    float ws3 = ok3 ? wsum[orow + 3] : 0.f;
#define EPI(ACC, ct)                                                          \
    {                                                                         \
        int c = (ct) * 16 + lrow;                                             \
        float bb = b0v[c], wb = bwv[c];                                       \
        float v0 = ok0 ? fmaxf(ACC[0] + bb + ws0 * wb, 0.f) : 0.f;            \
        float v1 = ok1 ? fmaxf(ACC[1] + bb + ws1 * wb, 0.f) : 0.f;            \
        float v2 = ok2 ? fmaxf(ACC[2] + bb + ws2 * wb, 0.f) : 0.f;            \
        float v3 = ok3 ? fmaxf(ACC[3] + bb + ws3 * wb, 0.f) : 0.f;            \
        if (ok0) out[(size_t)(orow + 0) * 64 + c] = f2b(v0);                  \
        if (ok1) out[(size_t)(orow + 1) * 64 + c] = f2b(v1);                  \
        if (ok2) out[(size_t)(orow + 2) * 64 + c] = f2b(v2);                  \
        if (ok3) out[(size_t)(orow + 3) * 64 + c] = f2b(v3);                  \
        if (statacc) {                                                        \
            float sv = (v0 + v1) + (v2 + v3);                                 \
            float qv = fmaf(v0, v0, fmaf(v1, v1, fmaf(v2, v2, v3 * v3)));     \
            sv += __shfl_xor(sv, 16); sv += __shfl_xor(sv, 32);               \
            qv += __shfl_xor(qv, 16); qv += __shfl_xor(qv, 32);               \
            if (lkg == 0) { lstat[wv][0][c] = sv; lstat[wv][1][c] = qv; }     \
        }                                                                     \
    }
    EPI(acc0, 0)
    EPI(acc1, 1)
    EPI(acc2, 2)
    EPI(acc3, 3)
#undef EPI
    if (statacc) {
        __syncthreads();
        if (t < 128) {
            int c = t & 63, p = t >> 6;
            atomicAdd(&statacc[p * 64 + c],
                      lstat[0][p][c] + lstat[1][p][c] + lstat[2][p][c] + lstat[3][p][c]);
        }
    }
}

// ---------------- pooling ----------------
__global__ __launch_bounds__(256) void k_seg_count(const int* __restrict__ batch, int n, int* __restrict__ cnt) {
    int i = blockIdx.x * blockDim.x + threadIdx.x;
    if (i >= n) return;
    int lane = threadIdx.x & 63;
    int b = batch[i];
    int bprev = __shfl_up(b, 1);
    bool head = (lane == 0) || (b != bprev);
    unsigned long long hb = __ballot(head);
    if (head) {
        unsigned long long mask = (lane == 63) ? 0ULL : (hb >> (lane + 1));
        int wstart = i - lane;
        int nvalid = min(64, n - wstart);
        int end = (mask == 0ULL) ? nvalid : (lane + 1 + __ffsll((long long)mask) - 1);
        atomicAdd(&cnt[b], end - lane);
    }
}

// bf16 features; 128 rows/block (32/walker); batch sorted -> ~1 run/walker
__global__ __launch_bounds__(256) void k_pool_accum(const u16* __restrict__ x, const int* __restrict__ batch,
                             int n, float* __restrict__ sums) {
    int c = threadIdx.x & 63, r4 = threadIdx.x >> 6;
    int base = blockIdx.x * 128 + r4 * 32;
    int end = min(n, base + 32);
    float acc = 0.f; int cur = -1;
    for (int i = base; i < end; ++i) {
        int b = batch[i];
        if (b != cur) {
            if (cur >= 0) atomicAdd(&sums[cur * 64 + c], acc);
            acc = 0.f; cur = b;
        }
        acc += b2f(x[(size_t)i * 64 + c]);
    }
    if (cur >= 0) atomicAdd(&sums[cur * 64 + c], acc);
}

__global__ __launch_bounds__(256) void k_pool_div(const float* __restrict__ sv, const float* __restrict__ sc,
                           const int* __restrict__ cv, const int* __restrict__ cc2,
                           float* __restrict__ out) {
    int idx = blockIdx.x * blockDim.x + threadIdx.x;
    if (idx >= NBb * 128) return;
    int b = idx >> 7, j = idx & 127;
    float v;
    if (j < 64) v = sv[b * 64 + j] / fmaxf((float)cv[b], 1.0f);
    else        v = sc[b * 64 + (j - 64)] / fmaxf((float)cc2[b], 1.0f);
    out[idx] = v;
}

// ==================================================================
extern "C" void kernel_launch(void* const* d_in, const int* in_sizes, int n_in,
                              void* d_out, int out_size, void* d_ws, size_t ws_size,
                              hipStream_t stream) {
    (void)in_sizes; (void)n_in; (void)out_size; (void)ws_size;
    const float* var_feats = (const float*)d_in[0];
    const float* cstr_feats = (const float*)d_in[1];
    const float* edge_attr = (const float*)d_in[2];
    const float* Wrel_v0 = (const float*)d_in[3];
    const float* brel_v0 = (const float*)d_in[4];
    const float* Wroot_v0 = (const float*)d_in[5];
    const float* Wrel_c0 = (const float*)d_in[6];
    const float* brel_c0 = (const float*)d_in[7];
    const float* Wroot_c0 = (const float*)d_in[8];
    const float* g_v0 = (const float*)d_in[9];
    const float* b_v0 = (const float*)d_in[10];
    const float* g_c0 = (const float*)d_in[11];
    const float* b_c0 = (const float*)d_in[12];
    const float* Wrel_v = (const float*)d_in[13];
    const float* brel_v = (const float*)d_in[14];
    const float* Wroot_v = (const float*)d_in[15];
    const float* Wrel_c = (const float*)d_in[16];
    const float* brel_c = (const float*)d_in[17];
    const float* Wroot_c = (const float*)d_in[18];
    const float* g_v = (const float*)d_in[19];
    const float* b_v = (const float*)d_in[20];
    const float* g_c = (const float*)d_in[21];
    const float* b_c = (const float*)d_in[22];
    const int* edge_index = (const int*)d_in[23];
    const int* var_batch = (const int*)d_in[24];
    const int* cstr_batch = (const int*)d_in[25];
    const int* src_c = edge_index;
    const int* dst_v = edge_index + NEn;
    float* out = (float*)d_out;

    // ---- workspace carve-out ----
    char* ws = (char*)d_ws;
    size_t off_b = 0;
    auto alloc = [&](size_t bytes) -> char* {
        char* p = ws + off_b;
        off_b = (off_b + bytes + 255) & ~(size_t)255;
        return p;
    };
    // bf16 feature ping-pong buffers
    u16* Vb[2] = { (u16*)alloc((size_t)NVn * 64 * 2), (u16*)alloc((size_t)NVn * 64 * 2) };
    u16* Cb[2] = { (u16*)alloc((size_t)NCn * 64 * 2), (u16*)alloc((size_t)NCn * 64 * 2) };
    // layer-0 f32 agg scratch (small D)
    float* aggV0 = (float*)alloc((size_t)NVn * 4);        // [NV,1]
    float* aggC0 = (float*)alloc((size_t)NCn * 9 * 4);    // [NC,9]
    int* off_v = (int*)alloc((size_t)(NVn + 1) * 4);
    int* cur_v = (int*)alloc((size_t)NVn * 4);
    int* col_v = (int*)alloc((size_t)NEn * 4);
    float* w_v = (float*)alloc((size_t)NEn * 4);
    int* off_c = (int*)alloc((size_t)(NCn + 1) * 4);
    int* cur_c = (int*)alloc((size_t)NCn * 4);
    int* col_c = (int*)alloc((size_t)NEn * 4);
    float* w_c = (float*)alloc((size_t)NEn * 4);
    float* wsum_v = (float*)alloc((size_t)NVn * 4);
    float* wsum_c = (float*)alloc((size_t)NCn * 4);
    int* degzone = (int*)alloc((size_t)(NVn + NCn) * 4);
    int* degv = degzone;
    int* degc = degzone + NVn;
    int* bsum = (int*)alloc(1024 * 4);
    // zero-init zone (one memset): stats accums + pool sums + counts
    float* zzone = (float*)alloc(4992 * 4);
    float* accL0v = zzone;            // 32 (18 used)
    float* accL0c = zzone + 32;       // 8 (2 used)
    float* accLv[3], *accLc[3];
    for (int l = 0; l < 3; l++) { accLv[l] = zzone + 64 + l * 256; accLc[l] = zzone + 64 + l * 256 + 128; }
    float* pool_sv = zzone + 832;     // 2048
    float* pool_sc = zzone + 2880;    // 2048
    int* cnt_v = (int*)(zzone + 4928);  // 32
    int* cnt_c = (int*)(zzone + 4960);  // 32
    // folded weights
    float* Wr_v = (float*)alloc(4096 * 4);
    float* Wt_v = (float*)alloc(4096 * 4);
    float* b0_v = (float*)alloc(64 * 4);
    float* bw_v = (float*)alloc(64 * 4);
    float* Wr_c = (float*)alloc(4096 * 4);
    float* Wt_c = (float*)alloc(4096 * 4);
    float* b0_c = (float*)alloc(64 * 4);
    float* bw_c = (float*)alloc(64 * 4);
    // bf16 MFMA B-fragment buffers: [ks4][ct4][lane64][8 bf16]
    u16* Bf_v = (u16*)alloc(8192 * 2);
    u16* Bf_c = (u16*)alloc(8192 * 2);

    const float invNV = 1.0f / (float)NVn;
    const float invNC = 1.0f / (float)NCn;

    // ---- init ----
    hipMemsetAsync(degzone, 0, (size_t)(NVn + NCn) * 4, stream);
    hipMemsetAsync(zzone, 0, 4992 * 4, stream);

    // ---- build CSR both directions ----
    k_count_deg<<<2048, 256, 0, stream>>>(src_c, dst_v, degv, degc);
    int nbv = (NVn + 1023) / 1024;  // 196
    int nbc = (NCn + 1023) / 1024;  // 98
    k_scan_block<<<nbv, 256, 0, stream>>>(degv, NVn, bsum);
    k_scan_tops<<<1, 1024, 0, stream>>>(bsum, nbv);
    k_scan_final<<<nbv, 256, 0, stream>>>(degv, NVn, bsum, off_v, cur_v);
    k_scan_block<<<nbc, 256, 0, stream>>>(degc, NCn, bsum);
    k_scan_tops<<<1, 1024, 0, stream>>>(bsum, nbc);
    k_scan_final<<<nbc, 256, 0, stream>>>(degc, NCn, bsum, off_c, cur_c);
    k_fill<<<2048, 256, 0, stream>>>(dst_v, src_c, edge_attr, off_v, cur_v, col_v, w_v);
    k_fill<<<2048, 256, 0, stream>>>(src_c, dst_v, edge_attr, off_c, cur_c, col_c, w_c);
    k_wsum<<<784, 256, 0, stream>>>(off_v, w_v, wsum_v, NVn);
    k_wsum<<<392, 256, 0, stream>>>(off_c, w_c, wsum_c, NCn);

    // ---- layer 0 (var: 9 feats, cstr: 1 feat) ----
    k_stats_small<9><<<784, 256, 0, stream>>>(var_feats, NVn, accL0v);
    k_stats_small<1><<<392, 256, 0, stream>>>(cstr_feats, NCn, accL0c);
    {
        FoldArgs fv = { Wrel_v0, brel_v0, Wroot_v0, g_c0, b_c0, accL0c, g_v0, b_v0, accL0v,
                        invNC, invNV, 1, 9, Wr_v, Wt_v, b0_v, bw_v, (u16*)nullptr };
        FoldArgs fc = { Wrel_c0, brel_c0, Wroot_c0, g_v0, b_v0, accL0v, g_c0, b_c0, accL0c,
                        invNV, invNC, 9, 1, Wr_c, Wt_c, b0_c, bw_c, (u16*)nullptr };
        k_fold2<<<2, 256, 0, stream>>>(fv, fc);
    }
    k_agg1<<<784, 256, 0, stream>>>(cstr_feats, off_v, col_v, w_v, aggV0, NVn);       // [NV,1]
    k_agg<9><<<2048, 256, 0, stream>>>(var_feats, off_c, col_c, w_c, aggC0, NCn);     // [NC,9]
    k_gemm0<1, 9><<<(NVn * 64 + 255) / 256, 256, 0, stream>>>(aggV0, var_feats, wsum_v,
                                                              Wr_v, Wt_v, b0_v, bw_v, Vb[0], NVn);
    k_gemm0<9, 1><<<(NCn * 64 + 255) / 256, 256, 0, stream>>>(aggC0, cstr_feats, wsum_c,
                                                              Wr_c, Wt_c, b0_c, bw_c, Cb[0], NCn);
    k_stats64b<<<2048, 256, 0, stream>>>(Vb[0], NVn, accLv[0]);
    k_stats64b<<<2048, 256, 0, stream>>>(Cb[0], NCn, accLc[0]);

    // ---- layers 1..3 (fused agg+GEMM+stats) ----
    int cur = 0;
    for (int l = 0; l < 3; l++) {
        const float* Wrv = Wrel_v + (size_t)l * 4096;
        const float* brv = brel_v + (size_t)l * 64;
        const float* Wtv = Wroot_v + (size_t)l * 4096;
        const float* Wrc = Wrel_c + (size_t)l * 4096;
        const float* brc = brel_c + (size_t)l * 64;
        const float* Wtc = Wroot_c + (size_t)l * 4096;
        const float* gvl = g_v + (size_t)l * 64; const float* bvl = b_v + (size_t)l * 64;
        const float* gcl = g_c + (size_t)l * 64; const float* bcl = b_c + (size_t)l * 64;

        FoldArgs fv = { Wrv, brv, Wtv, gcl, bcl, accLc[l], gvl, bvl, accLv[l],
                        invNC, invNV, 64, 64, Wr_v, Wt_v, b0_v, bw_v, Bf_v };
        FoldArgs fc = { Wrc, brc, Wtc, gvl, bvl, accLv[l], gcl, bcl, accLc[l],
                        invNV, invNC, 64, 64, Wr_c, Wt_c, b0_c, bw_c, Bf_c };
        k_fold2<<<2, 256, 0, stream>>>(fv, fc);

        int nxt = cur ^ 1;
        float* sv = (l < 2) ? accLv[l + 1] : (float*)nullptr;
        float* sc = (l < 2) ? accLc[l + 1] : (float*)nullptr;
        k_layer<<<(NVn + 63) / 64, 256, 0, stream>>>(Cb[cur], Vb[cur], off_v, col_v, w_v,
                                                     wsum_v, Bf_v, b0_v, bw_v, Vb[nxt], sv, NVn);
        k_layer<<<(NCn + 63) / 64, 256, 0, stream>>>(Vb[cur], Cb[cur], off_c, col_c, w_c,
                                                     wsum_c, Bf_c, b0_c, bw_c, Cb[nxt], sc, NCn);
        cur = nxt;
    }

    // ---- pooling ----
    k_seg_count<<<(NVn + 255) / 256, 256, 0, stream>>>(var_batch, NVn, cnt_v);
    k_seg_count<<<(NCn + 255) / 256, 256, 0, stream>>>(cstr_batch, NCn, cnt_c);
    k_pool_accum<<<(NVn + 127) / 128, 256, 0, stream>>>(Vb[cur], var_batch, NVn, pool_sv);
    k_pool_accum<<<(NCn + 127) / 128, 256, 0, stream>>>(Cb[cur], cstr_batch, NCn, pool_sc);
    k_pool_div<<<(NBb * 128 + 255) / 256, 256, 0, stream>>>(pool_sv, pool_sc, cnt_v, cnt_c, out);
}

// Round 14
// 964.557 us; speedup vs baseline: 1.3648x; 1.0193x over previous
//
#include <hip/hip_runtime.h>

// Problem constants (match reference setup_inputs)
constexpr int NVn = 200000;   // var nodes, 9 feats in
constexpr int NCn = 100000;   // cstr nodes, 1 feat in
constexpr int NEn = 1000000;  // edges
constexpr int NBb = 32;       // graphs
#define EPSf 1e-5f

typedef unsigned short u16;
typedef __attribute__((ext_vector_type(8))) short s8v;   // 8 bf16 (4 VGPRs)
typedef __attribute__((ext_vector_type(4))) float f4v;   // 4 f32 acc

// f32 -> bf16 bits, round-to-nearest-even
static __device__ __forceinline__ u16 f2b(float f) {
    union { float f; unsigned u; } x; x.f = f;
    return (u16)((x.u + 0x7FFFu + ((x.u >> 16) & 1u)) >> 16);
}
static __device__ __forceinline__ float b2f(u16 u) {
    union { unsigned u; float f; } x; x.u = ((unsigned)u) << 16; return x.f;
}

// store folded weight W[kg][h] (kg in 0..127, h in 0..63) into MFMA B-fragment order:
// fragment (ks=kg>>5, ct=h>>4), lane = ((kg>>3)&3)<<4 | (h&15), elem j = kg&7
static __device__ __forceinline__ void frag_store(u16* B, int kg, int h, float w) {
    int ks = kg >> 5, g = (kg >> 3) & 3, j = kg & 7, ct = h >> 4;
    int lane = (g << 4) | (h & 15);
    B[((((ks << 2) | ct) << 6) | lane) * 8 + j] = f2b(w);
}

// ---------------- degree count ----------------
__global__ __launch_bounds__(256) void k_count_deg(const int* __restrict__ src, const int* __restrict__ dst,
                            int* __restrict__ degv, int* __restrict__ degc) {
    for (int e = blockIdx.x * blockDim.x + threadIdx.x; e < NEn; e += gridDim.x * blockDim.x) {
        atomicAdd(&degv[dst[e]], 1);
        atomicAdd(&degc[src[e]], 1);
    }
}

// ---------------- exclusive scan (3 kernels, 1024 elems/block) ----------------
__global__ __launch_bounds__(256) void k_scan_block(const int* __restrict__ deg, int n, int* __restrict__ bsum) {
    __shared__ int s[256];
    int base = blockIdx.x * 1024;
    int t = threadIdx.x;
    int v = 0;
#pragma unroll
    for (int j = 0; j < 4; j++) { int idx = base + t * 4 + j; if (idx < n) v += deg[idx]; }
    s[t] = v; __syncthreads();
    for (int o = 128; o > 0; o >>= 1) { if (t < o) s[t] += s[t + o]; __syncthreads(); }
    if (t == 0) bsum[blockIdx.x] = s[0];
}

__global__ __launch_bounds__(1024) void k_scan_tops(int* bsum, int nb) {
    __shared__ int s[1024];
    int t = threadIdx.x;
    int v = (t < nb) ? bsum[t] : 0;
    s[t] = v; __syncthreads();
    for (int o = 1; o < 1024; o <<= 1) {
        int x = (t >= o) ? s[t - o] : 0; __syncthreads();
        s[t] += x; __syncthreads();
    }
    if (t < nb) bsum[t] = s[t] - v;  // exclusive
}

__global__ __launch_bounds__(256) void k_scan_final(const int* __restrict__ deg, int n, const int* __restrict__ bsum,
                             int* __restrict__ off, int* __restrict__ cur) {
    __shared__ int s[256];
    int base = blockIdx.x * 1024, t = threadIdx.x;
    int d[4], loc[4], sum = 0;
#pragma unroll
    for (int j = 0; j < 4; j++) {
        int idx = base + t * 4 + j;
        d[j] = (idx < n) ? deg[idx] : 0;
        loc[j] = sum; sum += d[j];
    }
    s[t] = sum; __syncthreads();
    int v = sum;
    for (int o = 1; o < 256; o <<= 1) {
        int x = (t >= o) ? s[t - o] : 0; __syncthreads();
        s[t] += x; __syncthreads();
    }
    int texcl = s[t] - v + bsum[blockIdx.x];
#pragma unroll
    for (int j = 0; j < 4; j++) {
        int idx = base + t * 4 + j;
        if (idx < n) {
            int o2 = texcl + loc[j];
            off[idx] = o2; cur[idx] = o2;
            if (idx == n - 1) off[n] = o2 + d[j];
        }
    }
}

// ---------------- CSR fill, BOTH directions in one pass (round-13) ----------------
// off is the scan of concat(deg_v, deg_c); v rows at [0,NVn), c rows at [NVn,NVn+NCn).
// erec[p] = {neighbor index, bits(ew/deg)} -- one 8B record per edge per direction.
__global__ __launch_bounds__(256) void k_fill_both(const int* __restrict__ src, const int* __restrict__ dst,
                       const float* __restrict__ ew, const int* __restrict__ off,
                       int* __restrict__ cur, int2* __restrict__ erec) {
    for (int e = blockIdx.x * blockDim.x + threadIdx.x; e < NEn; e += gridDim.x * blockDim.x) {
        int s = src[e], d = dst[e];
        float a = ew[e];
        int degv = off[d + 1] - off[d];
        int p = atomicAdd(&cur[d], 1);
        erec[p] = make_int2(s, __float_as_int(a * (1.0f / (float)degv)));
        int kc = NVn + s;
        int degc = off[kc + 1] - off[kc];
        int p2 = atomicAdd(&cur[kc], 1);
        erec[p2] = make_int2(d, __float_as_int(a * (1.0f / (float)degc)));
    }
}

__global__ __launch_bounds__(256) void k_wsum_rec(const int* __restrict__ off, const int2* __restrict__ erec,
                       float* __restrict__ ws, int n) {
    for (int i = blockIdx.x * blockDim.x + threadIdx.x; i < n; i += gridDim.x * blockDim.x) {
        int s = off[i], e = off[i + 1]; float t = 0.f;
        for (int j = s; j < e; j++) t += __int_as_float(erec[j].y);
        ws[i] = t;
    }
}

// ---------------- BN column stats (bf16 input) ----------------
__global__ __launch_bounds__(256) void k_stats64b(const u16* __restrict__ x, int n, float* __restrict__ acc) {
    int c = threadIdx.x & 63, r4 = threadIdx.x >> 6;
    float s = 0.f, q = 0.f;
    for (int i = blockIdx.x * 4 + r4; i < n; i += gridDim.x * 4) {
        float v = b2f(x[(size_t)i * 64 + c]); s += v; q = fmaf(v, v, q);
    }
    __shared__ float ls[512];
    ls[threadIdx.x] = s; ls[256 + threadIdx.x] = q;
    __syncthreads();
    if (r4 == 0) {
        atomicAdd(&acc[c], ls[c] + ls[c + 64] + ls[c + 128] + ls[c + 192]);
        atomicAdd(&acc[64 + c], ls[256 + c] + ls[256 + c + 64] + ls[256 + c + 128] + ls[256 + c + 192]);
    }
}

// f32 input, small D: 1 row/thread, wave shuffle-reduce, 2D atomics/block
template <int D>
__global__ __launch_bounds__(256) void k_stats_small(const float* __restrict__ x, int n, float* __restrict__ acc) {
    float s[D], q[D];
#pragma unroll
    for (int k = 0; k < D; k++) { s[k] = 0.f; q[k] = 0.f; }
    for (int i = blockIdx.x * blockDim.x + threadIdx.x; i < n; i += gridDim.x * blockDim.x) {
#pragma unroll
        for (int k = 0; k < D; k++) { float v = x[(size_t)i * D + k]; s[k] += v; q[k] = fmaf(v, v, q[k]); }
    }
#pragma unroll
    for (int k = 0; k < D; k++) {
#pragma unroll
        for (int o = 32; o > 0; o >>= 1) {
            s[k] += __shfl_down(s[k], o);
            q[k] += __shfl_down(q[k], o);
        }
    }
    __shared__ float ls[4][2 * D];
    int lane = threadIdx.x & 63, wv = threadIdx.x >> 6;
    if (lane == 0) {
#pragma unroll
        for (int k = 0; k < D; k++) { ls[wv][k] = s[k]; ls[wv][D + k] = q[k]; }
    }
    __syncthreads();
    int t = threadIdx.x;
    if (t < 2 * D) atomicAdd(&acc[t], ls[0][t] + ls[1][t] + ls[2][t] + ls[3][t]);
}

// ---------------- fold BN into weights (2 param sets in one launch; block 0=A, 1=B) ------
struct FoldArgs {
    const float *Wrel, *brel, *Wroot, *gs, *bs, *accs, *gd, *bd, *accd;
    float invNs, invNd;
    int DSv, DDv;
    float *Wr_o, *Wt_o, *b0_o, *bw_o;
    u16* Bfrag;
};

__global__ __launch_bounds__(256) void k_fold2(FoldArgs A, FoldArgs B) {
    const FoldArgs F = blockIdx.x ? B : A;
    __shared__ float sa[128], sbe[128];
    __shared__ float rb0[4][64], rbw[4][64];
    int t = threadIdx.x;
    int total = F.DSv + F.DDv;
    for (int k = t; k < total; k += 256) {
        bool isrc = k < F.DSv;
        int kk = isrc ? k : k - F.DSv;
        const float* acc = isrc ? F.accs : F.accd;
        float invN = isrc ? F.invNs : F.invNd;
        int D = isrc ? F.DSv : F.DDv;
        float g = isrc ? F.gs[kk] : F.gd[kk];
        float b = isrc ? F.bs[kk] : F.bd[kk];
        float m = acc[kk] * invN;
        float var = acc[D + kk] * invN - m * m;
        float a = g * rsqrtf(var + EPSf);
        sa[k] = a; sbe[k] = b - m * a;
    }
    __syncthreads();
    int h = t & 63, q = t >> 6;
    float bw = 0.f, b0 = 0.f;
    for (int k = q; k < F.DSv; k += 4) {
        float wv = F.Wrel[k * 64 + h];
        float wf = sa[k] * wv;
        F.Wr_o[k * 64 + h] = wf;
        bw = fmaf(sbe[k], wv, bw);
        if (F.Bfrag) frag_store(F.Bfrag, k, h, wf);
    }
    for (int k = q; k < F.DDv; k += 4) {
        float wv = F.Wroot[k * 64 + h];
        float wf = sa[F.DSv + k] * wv;
        F.Wt_o[k * 64 + h] = wf;
        b0 = fmaf(sbe[F.DSv + k], wv, b0);
        if (F.Bfrag) frag_store(F.Bfrag, 64 + k, h, wf);
    }
    rb0[q][h] = b0; rbw[q][h] = bw;
    __syncthreads();
    if (q == 0) {
        F.b0_o[h] = F.brel[h] + rb0[0][h] + rb0[1][h] + rb0[2][h] + rb0[3][h];
        F.bw_o[h] = rbw[0][h] + rbw[1][h] + rbw[2][h] + rbw[3][h];
    }
}

// ---------------- layer-0 helpers (erec-based) ----------------
template <int DS>
__global__ __launch_bounds__(256) void k_agg(const float* __restrict__ xs, const int* __restrict__ off,
                      const int2* __restrict__ erec, float* __restrict__ agg, int n) {
    int lane = threadIdx.x & 63;
    int wid = (blockIdx.x * blockDim.x + threadIdx.x) >> 6;
    int nw = (gridDim.x * blockDim.x) >> 6;
    for (int i = wid; i < n; i += nw) {
        int s = off[i], e = off[i + 1];
        if (lane < DS) {
            float a0 = 0.f, a1 = 0.f;
            int j = s;
            for (; j + 1 < e; j += 2) {
                int2 r0 = erec[j], r1 = erec[j + 1];
                a0 = fmaf(__int_as_float(r0.y), xs[(size_t)r0.x * DS + lane], a0);
                a1 = fmaf(__int_as_float(r1.y), xs[(size_t)r1.x * DS + lane], a1);
            }
            if (j < e) { int2 r0 = erec[j]; a0 = fmaf(__int_as_float(r0.y), xs[(size_t)r0.x * DS + lane], a0); }
            agg[(size_t)i * DS + lane] = a0 + a1;
        }
    }
}

__global__ __launch_bounds__(256) void k_agg1(const float* __restrict__ xs, const int* __restrict__ off,
                       const int2* __restrict__ erec, float* __restrict__ agg, int n) {
    for (int i = blockIdx.x * blockDim.x + threadIdx.x; i < n; i += gridDim.x * blockDim.x) {
        int s = off[i], e = off[i + 1]; float a = 0.f;
        for (int j = s; j < e; j++) { int2 r = erec[j]; a = fmaf(__int_as_float(r.y), xs[r.x], a); }
        agg[i] = a;
    }
}

// layer-0 small-K GEMM: thread per (node, h); bf16 output
template <int KS, int KD>
__global__ __launch_bounds__(256) void k_gemm0(const float* __restrict__ aggs, const float* __restrict__ xd,
                        const float* __restrict__ wsum,
                        const float* __restrict__ Wr, const float* __restrict__ Wt,
                        const float* __restrict__ b0, const float* __restrict__ bw,
                        u16* __restrict__ out, int n) {
    int idx = blockIdx.x * blockDim.x + threadIdx.x;
    int i = idx >> 6, h = idx & 63;
    if (i >= n) return;
    float acc = b0[h] + wsum[i] * bw[h];
#pragma unroll
    for (int k = 0; k < KS; k++) acc = fmaf(aggs[i * KS + k], Wr[k * 64 + h], acc);
#pragma unroll
    for (int k = 0; k < KD; k++) acc = fmaf(xd[i * KD + k], Wt[k * 64 + h], acc);
    out[(size_t)i * 64 + h] = f2b(fmaxf(acc, 0.0f));
}

// ---------------- FUSED layer: agg (gather) + MFMA GEMM + epilogue + next-layer BN stats ----
// NB = 4-edge groups in fast path (2 for v deg~5, 4 for c deg~10). Constant 16 gathers
// in flight: rows-per-batch = 16/NB. Edge meta via one int2 load (round-13).
template <int NB>
__global__ __launch_bounds__(256, 2) void k_layer(
        const u16* __restrict__ xs, const u16* __restrict__ xr,
        const int* __restrict__ off, const int2* __restrict__ erec,
        const float* __restrict__ wsum, const u16* __restrict__ Bfrag,
        const float* __restrict__ b0v, const float* __restrict__ bwv,
        u16* __restrict__ out, float* __restrict__ statacc, int n) {
    constexpr int RPB = 16 / NB;   // rows per batch
    __shared__ __align__(16) u16 lagg[4][16][72];
    __shared__ float lstat[4][2][64];
    int t = threadIdx.x;
    int wv = t >> 6, l = t & 63;
    int lrow = l & 15, lkg = l >> 4;
    int base = blockIdx.x * 64 + wv * 16;
    // phase 1: aggregate
    {
        int g = l >> 4, qi = l & 15;
        int offv = 0;
        if (l < 17) { int idx = base + l; offv = off[idx > n ? n : idx]; }
#pragma unroll
        for (int ob = 0; ob < NB; ++ob) {
            int s_[RPB], e_[RPB];
            int cc[RPB][NB];
            float ww[RPB][NB];
#pragma unroll
            for (int rr = 0; rr < RPB; ++rr) {
                int r = ob * RPB + rr;
                int s = __shfl(offv, r);
                int e = __shfl(offv, r + 1);
                s_[rr] = s; e_[rr] = e;
#pragma unroll
                for (int b = 0; b < NB; ++b) {
                    int d = e - s - 4 * b;
                    int idx = (d > 0) ? (s + 4 * b + (g < d ? g : 0)) : 0;
                    int2 rec = erec[idx];
                    cc[rr][b] = rec.x;
                    float wv2 = __int_as_float(rec.y);
                    if (g >= d) wv2 = 0.f;
                    ww[rr][b] = wv2;
                }
            }
            ushort4 ft[RPB][NB];
#pragma unroll
            for (int rr = 0; rr < RPB; ++rr)
#pragma unroll
                for (int b = 0; b < NB; ++b)
                    ft[rr][b] = *(const ushort4*)(xs + (size_t)cc[rr][b] * 64 + qi * 4);
#pragma unroll
            for (int rr = 0; rr < RPB; ++rr) {
                float a0 = 0.f, a1 = 0.f, a2 = 0.f, a3 = 0.f;
#pragma unroll
                for (int b = 0; b < NB; ++b) {
                    a0 = fmaf(ww[rr][b], b2f(ft[rr][b].x), a0);
                    a1 = fmaf(ww[rr][b], b2f(ft[rr][b].y), a1);
                    a2 = fmaf(ww[rr][b], b2f(ft[rr][b].z), a2);
                    a3 = fmaf(ww[rr][b], b2f(ft[rr][b].w), a3);
                }
                for (int j = s_[rr] + 4 * NB; j < e_[rr]; j += 4) {
                    int rem = e_[rr] - j;
                    int i2 = j + (g < rem ? g : 0);
                    int2 rec = erec[i2];
                    float w2 = __int_as_float(rec.y); if (g >= rem) w2 = 0.f;
                    ushort4 f2 = *(const ushort4*)(xs + (size_t)rec.x * 64 + qi * 4);
                    a0 = fmaf(w2, b2f(f2.x), a0);
                    a1 = fmaf(w2, b2f(f2.y), a1);
                    a2 = fmaf(w2, b2f(f2.z), a2);
                    a3 = fmaf(w2, b2f(f2.w), a3);
                }
                a0 += __shfl_xor(a0, 16); a0 += __shfl_xor(a0, 32);
                a1 += __shfl_xor(a1, 16); a1 += __shfl_xor(a1, 32);
                a2 += __shfl_xor(a2, 16); a2 += __shfl_xor(a2, 32);
                a3 += __shfl_xor(a3, 16); a3 += __shfl_xor(a3, 32);
                if (g == 0) {
                    ushort4 o;
                    o.x = f2b(a0); o.y = f2b(a1); o.z = f2b(a2); o.w = f2b(a3);
                    *(ushort4*)&lagg[wv][ob * RPB + rr][qi * 4] = o;
                }
            }
        }
    }
    // phase 2: MFMA (per-wave LDS region: wave-synchronous, no barrier needed)
    const u16* Bl = Bfrag + l * 8;
    f4v acc0 = {0.f, 0.f, 0.f, 0.f};
    f4v acc1 = acc0, acc2 = acc0, acc3 = acc0;
#define LSTEP(ks, APTR)                                                       \
    {                                                                         \
        s8v a = *(const s8v*)(APTR);                                          \
        s8v f0 = *(const s8v*)(Bl + ((ks) * 4 + 0) * 512);                    \
        s8v f1 = *(const s8v*)(Bl + ((ks) * 4 + 1) * 512);                    \
        s8v f2 = *(const s8v*)(Bl + ((ks) * 4 + 2) * 512);                    \
        s8v f3 = *(const s8v*)(Bl + ((ks) * 4 + 3) * 512);                    \
        acc0 = __builtin_amdgcn_mfma_f32_16x16x32_bf16(a, f0, acc0, 0, 0, 0); \
        acc1 = __builtin_amdgcn_mfma_f32_16x16x32_bf16(a, f1, acc1, 0, 0, 0); \
        acc2 = __builtin_amdgcn_mfma_f32_16x16x32_bf16(a, f2, acc2, 0, 0, 0); \
        acc3 = __builtin_amdgcn_mfma_f32_16x16x32_bf16(a, f3, acc3, 0, 0, 0); \
    }
    LSTEP(0, &lagg[wv][lrow][lkg * 8])
    LSTEP(1, &lagg[wv][lrow][32 + lkg * 8])
    int arow = base + lrow; if (arow >= n) arow = 0;
    const u16* xp = xr + (size_t)arow * 64 + lkg * 8;
    LSTEP(2, xp)
    LSTEP(3, xp + 32)
#undef LSTEP
    // phase 3: epilogue + stats
    int orow = base + lkg * 4;
    bool ok0 = orow + 0 < n, ok1 = orow + 1 < n, ok2 = orow + 2 < n, ok3 = orow + 3 < n;
    float ws0 = ok0 ? wsum[orow + 0] : 0.f;
    float ws1 = ok1 ? wsum[orow + 1] : 0.f;
    float ws2 = ok2 ? wsum[orow + 2] : 0.f;
    float ws3 = ok3 ? wsum[orow + 3] : 0.f;
#define EPI(ACC, ct)                                                          \
    {                                                                         \
        int c = (ct) * 16 + lrow;                                             \
        float bb = b0v[c], wb = bwv[c];                                       \
        float v0 = ok0 ? fmaxf(ACC[0] + bb + ws0 * wb, 0.f) : 0.f;            \
        float v1 = ok1 ? fmaxf(ACC[1] + bb + ws1 * wb, 0.f) : 0.f;            \
        float v2 = ok2 ? fmaxf(ACC[2] + bb + ws2 * wb, 0.f) : 0.f;            \
        float v3 = ok3 ? fmaxf(ACC[3] + bb + ws3 * wb, 0.f) : 0.f;            \
        if (ok0) out[(size_t)(orow + 0) * 64 + c] = f2b(v0);                  \
        if (ok1) out[(size_t)(orow + 1) * 64 + c] = f2b(v1);                  \
        if (ok2) out[(size_t)(orow + 2) * 64 + c] = f2b(v2);                  \
        if (ok3) out[(size_t)(orow + 3) * 64 + c] = f2b(v3);                  \
        if (statacc) {                                                        \
            float sv = (v0 + v1) + (v2 + v3);                                 \
            float qv = fmaf(v0, v0, fmaf(v1, v1, fmaf(v2, v2, v3 * v3)));     \
            sv += __shfl_xor(sv, 16); sv += __shfl_xor(sv, 32);               \
            qv += __shfl_xor(qv, 16); qv += __shfl_xor(qv, 32);               \
            if (lkg == 0) { lstat[wv][0][c] = sv; lstat[wv][1][c] = qv; }     \
        }                                                                     \
    }
    EPI(acc0, 0)
    EPI(acc1, 1)
    EPI(acc2, 2)
    EPI(acc3, 3)
#undef EPI
    if (statacc) {
        __syncthreads();
        if (t < 128) {
            int c = t & 63, p = t >> 6;
            atomicAdd(&statacc[p * 64 + c],
                      lstat[0][p][c] + lstat[1][p][c] + lstat[2][p][c] + lstat[3][p][c]);
        }
    }
}

// ---------------- pooling ----------------
__global__ __launch_bounds__(256) void k_seg_count(const int* __restrict__ batch, int n, int* __restrict__ cnt) {
    int i = blockIdx.x * blockDim.x + threadIdx.x;
    if (i >= n) return;
    int lane = threadIdx.x & 63;
    int b = batch[i];
    int bprev = __shfl_up(b, 1);
    bool head = (lane == 0) || (b != bprev);
    unsigned long long hb = __ballot(head);
    if (head) {
        unsigned long long mask = (lane == 63) ? 0ULL : (hb >> (lane + 1));
        int wstart = i - lane;
        int nvalid = min(64, n - wstart);
        int end = (mask == 0ULL) ? nvalid : (lane + 1 + __ffsll((long long)mask) - 1);
        atomicAdd(&cnt[b], end - lane);
    }
}

// bf16 features; 128 rows/block (32/walker); batch sorted -> ~1 run/walker
__global__ __launch_bounds__(256) void k_pool_accum(const u16* __restrict__ x, const int* __restrict__ batch,
                             int n, float* __restrict__ sums) {
    int c = threadIdx.x & 63, r4 = threadIdx.x >> 6;
    int base = blockIdx.x * 128 + r4 * 32;
    int end = min(n, base + 32);
    float acc = 0.f; int cur = -1;
    for (int i = base; i < end; ++i) {
        int b = batch[i];
        if (b != cur) {
            if (cur >= 0) atomicAdd(&sums[cur * 64 + c], acc);
            acc = 0.f; cur = b;
        }
        acc += b2f(x[(size_t)i * 64 + c]);
    }
    if (cur >= 0) atomicAdd(&sums[cur * 64 + c], acc);
}

__global__ __launch_bounds__(256) void k_pool_div(const float* __restrict__ sv, const float* __restrict__ sc,
                           const int* __restrict__ cv, const int* __restrict__ cc2,
                           float* __restrict__ out) {
    int idx = blockIdx.x * blockDim.x + threadIdx.x;
    if (idx >= NBb * 128) return;
    int b = idx >> 7, j = idx & 127;
    float v;
    if (j < 64) v = sv[b * 64 + j] / fmaxf((float)cv[b], 1.0f);
    else        v = sc[b * 64 + (j - 64)] / fmaxf((float)cc2[b], 1.0f);
    out[idx] = v;
}

// ==================================================================
extern "C" void kernel_launch(void* const* d_in, const int* in_sizes, int n_in,
                              void* d_out, int out_size, void* d_ws, size_t ws_size,
                              hipStream_t stream) {
    (void)in_sizes; (void)n_in; (void)out_size; (void)ws_size;
    const float* var_feats = (const float*)d_in[0];
    const float* cstr_feats = (const float*)d_in[1];
    const float* edge_attr = (const float*)d_in[2];
    const float* Wrel_v0 = (const float*)d_in[3];
    const float* brel_v0 = (const float*)d_in[4];
    const float* Wroot_v0 = (const float*)d_in[5];
    const float* Wrel_c0 = (const float*)d_in[6];
    const float* brel_c0 = (const float*)d_in[7];
    const float* Wroot_c0 = (const float*)d_in[8];
    const float* g_v0 = (const float*)d_in[9];
    const float* b_v0 = (const float*)d_in[10];
    const float* g_c0 = (const float*)d_in[11];
    const float* b_c0 = (const float*)d_in[12];
    const float* Wrel_v = (const float*)d_in[13];
    const float* brel_v = (const float*)d_in[14];
    const float* Wroot_v = (const float*)d_in[15];
    const float* Wrel_c = (const float*)d_in[16];
    const float* brel_c = (const float*)d_in[17];
    const float* Wroot_c = (const float*)d_in[18];
    const float* g_v = (const float*)d_in[19];
    const float* b_v = (const float*)d_in[20];
    const float* g_c = (const float*)d_in[21];
    const float* b_c = (const float*)d_in[22];
    const int* edge_index = (const int*)d_in[23];
    const int* var_batch = (const int*)d_in[24];
    const int* cstr_batch = (const int*)d_in[25];
    const int* src_c = edge_index;
    const int* dst_v = edge_index + NEn;
    float* out = (float*)d_out;

    // ---- workspace carve-out ----
    char* ws = (char*)d_ws;
    size_t off_b = 0;
    auto alloc = [&](size_t bytes) -> char* {
        char* p = ws + off_b;
        off_b = (off_b + bytes + 255) & ~(size_t)255;
        return p;
    };
    // bf16 feature ping-pong buffers
    u16* Vb[2] = { (u16*)alloc((size_t)NVn * 64 * 2), (u16*)alloc((size_t)NVn * 64 * 2) };
    u16* Cb[2] = { (u16*)alloc((size_t)NCn * 64 * 2), (u16*)alloc((size_t)NCn * 64 * 2) };
    // layer-0 f32 agg scratch (small D)
    float* aggV0 = (float*)alloc((size_t)NVn * 4);        // [NV,1]
    float* aggC0 = (float*)alloc((size_t)NCn * 9 * 4);    // [NC,9]
    // unified CSR: v rows [0,NVn), c rows [NVn,NVn+NCn); erec = 2M interleaved records
    constexpr int NT = NVn + NCn;
    int* off_all = (int*)alloc((size_t)(NT + 1) * 4);
    int* cur_all = (int*)alloc((size_t)NT * 4);
    int2* erec = (int2*)alloc((size_t)(2 * NEn) * 8);
    float* wsum_all = (float*)alloc((size_t)NT * 4);
    int* degzone = (int*)alloc((size_t)NT * 4);
    int* degv = degzone;
    int* degc = degzone + NVn;
    int* bsum = (int*)alloc(1024 * 4);
    // zero-init zone (one memset): stats accums + pool sums + counts
    float* zzone = (float*)alloc(4992 * 4);
    float* accL0v = zzone;            // 32 (18 used)
    float* accL0c = zzone + 32;       // 8 (2 used)
    float* accLv[3], *accLc[3];
    for (int l = 0; l < 3; l++) { accLv[l] = zzone + 64 + l * 256; accLc[l] = zzone + 64 + l * 256 + 128; }
    float* pool_sv = zzone + 832;     // 2048
    float* pool_sc = zzone + 2880;    // 2048
    int* cnt_v = (int*)(zzone + 4928);  // 32
    int* cnt_c = (int*)(zzone + 4960);  // 32
    // folded weights
    float* Wr_v = (float*)alloc(4096 * 4);
    float* Wt_v = (float*)alloc(4096 * 4);
    float* b0_v = (float*)alloc(64 * 4);
    float* bw_v = (float*)alloc(64 * 4);
    float* Wr_c = (float*)alloc(4096 * 4);
    float* Wt_c = (float*)alloc(4096 * 4);
    float* b0_c = (float*)alloc(64 * 4);
    float* bw_c = (float*)alloc(64 * 4);
    // bf16 MFMA B-fragment buffers: [ks4][ct4][lane64][8 bf16]
    u16* Bf_v = (u16*)alloc(8192 * 2);
    u16* Bf_c = (u16*)alloc(8192 * 2);

    const float invNV = 1.0f / (float)NVn;
    const float invNC = 1.0f / (float)NCn;
    const int* off_v = off_all;
    const int* off_c = off_all + NVn;
    float* wsum_v = wsum_all;
    float* wsum_c = wsum_all + NVn;

    // ---- init ----
    hipMemsetAsync(degzone, 0, (size_t)NT * 4, stream);
    hipMemsetAsync(zzone, 0, 4992 * 4, stream);

    // ---- build unified CSR (one scan + one fill for both directions) ----
    k_count_deg<<<2048, 256, 0, stream>>>(src_c, dst_v, degv, degc);
    int nbt = (NT + 1023) / 1024;  // 293
    k_scan_block<<<nbt, 256, 0, stream>>>(degzone, NT, bsum);
    k_scan_tops<<<1, 1024, 0, stream>>>(bsum, nbt);
    k_scan_final<<<nbt, 256, 0, stream>>>(degzone, NT, bsum, off_all, cur_all);
    k_fill_both<<<2048, 256, 0, stream>>>(src_c, dst_v, edge_attr, off_all, cur_all, erec);
    k_wsum_rec<<<(NT + 255) / 256, 256, 0, stream>>>(off_all, erec, wsum_all, NT);

    // ---- layer 0 (var: 9 feats, cstr: 1 feat) ----
    k_stats_small<9><<<784, 256, 0, stream>>>(var_feats, NVn, accL0v);
    k_stats_small<1><<<392, 256, 0, stream>>>(cstr_feats, NCn, accL0c);
    {
        FoldArgs fv = { Wrel_v0, brel_v0, Wroot_v0, g_c0, b_c0, accL0c, g_v0, b_v0, accL0v,
                        invNC, invNV, 1, 9, Wr_v, Wt_v, b0_v, bw_v, (u16*)nullptr };
        FoldArgs fc = { Wrel_c0, brel_c0, Wroot_c0, g_v0, b_v0, accL0v, g_c0, b_c0, accL0c,
                        invNV, invNC, 9, 1, Wr_c, Wt_c, b0_c, bw_c, (u16*)nullptr };
        k_fold2<<<2, 256, 0, stream>>>(fv, fc);
    }
    k_agg1<<<784, 256, 0, stream>>>(cstr_feats, off_v, erec, aggV0, NVn);       // [NV,1]
    k_agg<9><<<2048, 256, 0, stream>>>(var_feats, off_c, erec, aggC0, NCn);     // [NC,9]
    k_gemm0<1, 9><<<(NVn * 64 + 255) / 256, 256, 0, stream>>>(aggV0, var_feats, wsum_v,
                                                              Wr_v, Wt_v, b0_v, bw_v, Vb[0], NVn);
    k_gemm0<9, 1><<<(NCn * 64 + 255) / 256, 256, 0, stream>>>(aggC0, cstr_feats, wsum_c,
                                                              Wr_c, Wt_c, b0_c, bw_c, Cb[0], NCn);
    k_stats64b<<<2048, 256, 0, stream>>>(Vb[0], NVn, accLv[0]);
    k_stats64b<<<2048, 256, 0, stream>>>(Cb[0], NCn, accLc[0]);

    // ---- layers 1..3 (fused agg+GEMM+stats) ----
    int cur = 0;
    for (int l = 0; l < 3; l++) {
        const float* Wrv = Wrel_v + (size_t)l * 4096;
        const float* brv = brel_v + (size_t)l * 64;
        const float* Wtv = Wroot_v + (size_t)l * 4096;
        const float* Wrc = Wrel_c + (size_t)l * 4096;
        const float* brc = brel_c + (size_t)l * 64;
        const float* Wtc = Wroot_c + (size_t)l * 4096;
        const float* gvl = g_v + (size_t)l * 64; const float* bvl = b_v + (size_t)l * 64;
        const float* gcl = g_c + (size_t)l * 64; const float* bcl = b_c + (size_t)l * 64;

        FoldArgs fv = { Wrv, brv, Wtv, gcl, bcl, accLc[l], gvl, bvl, accLv[l],
                        invNC, invNV, 64, 64, Wr_v, Wt_v, b0_v, bw_v, Bf_v };
        FoldArgs fc = { Wrc, brc, Wtc, gvl, bvl, accLv[l], gcl, bcl, accLc[l],
                        invNV, invNC, 64, 64, Wr_c, Wt_c, b0_c, bw_c, Bf_c };
        k_fold2<<<2, 256, 0, stream>>>(fv, fc);

        int nxt = cur ^ 1;
        float* sv = (l < 2) ? accLv[l + 1] : (float*)nullptr;
        float* sc = (l < 2) ? accLc[l + 1] : (float*)nullptr;
        k_layer<2><<<(NVn + 63) / 64, 256, 0, stream>>>(Cb[cur], Vb[cur], off_v, erec,
                                                        wsum_v, Bf_v, b0_v, bw_v, Vb[nxt], sv, NVn);
        k_layer<4><<<(NCn + 63) / 64, 256, 0, stream>>>(Vb[cur], Cb[cur], off_c, erec,
                                                        wsum_c, Bf_c, b0_c, bw_c, Cb[nxt], sc, NCn);
        cur = nxt;
    }

    // ---- pooling ----
    k_seg_count<<<(NVn + 255) / 256, 256, 0, stream>>>(var_batch, NVn, cnt_v);
    k_seg_count<<<(NCn + 255) / 256, 256, 0, stream>>>(cstr_batch, NCn, cnt_c);
    k_pool_accum<<<(NVn + 127) / 128, 256, 0, stream>>>(Vb[cur], var_batch, NVn, pool_sv);
    k_pool_accum<<<(NCn + 127) / 128, 256, 0, stream>>>(Cb[cur], cstr_batch, NCn, pool_sc);
    k_pool_div<<<(NBb * 128 + 255) / 256, 256, 0, stream>>>(pool_sv, pool_sc, cnt_v, cnt_c, out);
}